// Round 8
// baseline (767.384 us; speedup 1.0000x reference)
//
#include <hip/hip_runtime.h>
#include <hip/hip_bf16.h>
#include <hip/hip_cooperative_groups.h>

namespace cg = cooperative_groups;

#define N_NODES 100000
#define N_EDGES 1000000
// P row layout per node (f16): [A' = Wc1a@z + b_c1 (128)] [B = Wc1b@z (128)]
//                              [Y = Wb@z (128)]            [Zh = f16(z) (128)]
#define PROW 512
#define NB (N_EDGES / 16)       // 62500

typedef float f32x4 __attribute__((ext_vector_type(4)));
typedef _Float16 f16x8 __attribute__((ext_vector_type(8)));
typedef _Float16 f16x2 __attribute__((ext_vector_type(2)));

__device__ inline f16x8 pack8(float4 a, float4 b) {
    f16x8 o;
    o[0] = (_Float16)a.x; o[1] = (_Float16)a.y; o[2] = (_Float16)a.z; o[3] = (_Float16)a.w;
    o[4] = (_Float16)b.x; o[5] = (_Float16)b.y; o[6] = (_Float16)b.z; o[7] = (_Float16)b.w;
    return o;
}
__device__ inline void mfma16(f32x4& acc, f16x8 a, f16x8 b) {
    acc = __builtin_amdgcn_mfma_f32_16x16x32_f16(a, b, acc, 0, 0, 0);
}
__device__ inline float fdot2(f16x8 a, f16x8 b, int j2, float c) {
    f16x2 pa = { a[2 * j2], a[2 * j2 + 1] };
    f16x2 pb = { b[2 * j2], b[2 * j2 + 1] };
    return __builtin_amdgcn_fdot2(pa, pb, c, false);
}

// ---- precompute (round-2 structure, measured ~35us): P cols 0..383 = Z @ W_all^T ----
__global__ __launch_bounds__(256) void precomp_kernel(
    const float* __restrict__ z, const float* __restrict__ w_c1,
    const float* __restrict__ b_c1, const float* __restrict__ w_b,
    _Float16* __restrict__ P)
{
    const int lane = threadIdx.x & 63;
    const int r = lane & 15, g = lane >> 4;
    const int wid = blockIdx.x * 4 + (threadIdx.x >> 6);
    const int ct = wid % 6;          // 6 col-tiles of 64 over 384 output cols
    const int walker = wid / 6;
    const int nWalk = (gridDim.x * 4) / 6;

    f16x8 bw[4][4];                  // B-fragments, loaded once
#pragma unroll
    for (int nt = 0; nt < 4; ++nt) {
        const int c = ct * 64 + nt * 16 + r;
        const float* wrow;
        if (c < 128)       wrow = w_c1 + (size_t)c * 256;               // Wc1a row
        else if (c < 256)  wrow = w_c1 + (size_t)(c - 128) * 256 + 128; // Wc1b row
        else               wrow = w_b + (size_t)(c - 256) * 128;        // Wb row
#pragma unroll
        for (int kk = 0; kk < 4; ++kk) {
            const int k0 = kk * 32 + g * 8;
            float4 f0 = *reinterpret_cast<const float4*>(wrow + k0);
            float4 f1 = *reinterpret_cast<const float4*>(wrow + k0 + 4);
            bw[nt][kk] = pack8(f0, f1);
        }
    }
    float bc1v[4] = {0.f, 0.f, 0.f, 0.f};
    if (ct < 2) {
#pragma unroll
        for (int nt = 0; nt < 4; ++nt) bc1v[nt] = b_c1[ct * 64 + nt * 16 + r];
    }

    for (int nb = walker; nb < N_NODES / 16; nb += nWalk) {
        const float* zp = z + (size_t)(nb * 16 + r) * 128;
        f32x4 acc[4] = {};
#pragma unroll
        for (int kk = 0; kk < 4; ++kk) {
            const int k0 = kk * 32 + g * 8;
            float4 z0 = *reinterpret_cast<const float4*>(zp + k0);
            float4 z1 = *reinterpret_cast<const float4*>(zp + k0 + 4);
            f16x8 a = pack8(z0, z1);
#pragma unroll
            for (int nt = 0; nt < 4; ++nt) mfma16(acc[nt], a, bw[nt][kk]);
        }
#pragma unroll
        for (int nt = 0; nt < 4; ++nt) {
#pragma unroll
            for (int rr = 0; rr < 4; ++rr) {
                const int node = nb * 16 + g * 4 + rr;
                const int col = ct * 64 + nt * 16 + r;
                P[(size_t)node * PROW + col] = (_Float16)(acc[nt][rr] + bc1v[nt]);
            }
        }
    }
}

// ---- Zh: f16 copy of z into P cols 384..511 (round-2 structure) ----
__global__ __launch_bounds__(256) void zb_kernel(const float* __restrict__ z,
                                                 _Float16* __restrict__ P)
{
    const int i = blockIdx.x * 256 + threadIdx.x;
    if (i >= N_NODES * 16) return;
    const int node = i >> 4, ch = i & 15;
    const float* zp = z + (size_t)node * 128 + ch * 8;
    float4 a = *reinterpret_cast<const float4*>(zp);
    float4 b = *reinterpret_cast<const float4*>(zp + 4);
    *reinterpret_cast<f16x8*>(P + (size_t)node * PROW + 384 + ch * 8) = pack8(a, b);
}

// ---------------- cooperative one-shot counting sort by dst ----------------
__global__ __launch_bounds__(256) void sort_kernel(
    const int* __restrict__ edge, int* __restrict__ counts, int* __restrict__ offs,
    int* __restrict__ partial, int2* __restrict__ sE, int* __restrict__ sOrig)
{
    cg::grid_group grid = cg::this_grid();
    const int tid = threadIdx.x, bid = blockIdx.x;
    const int nblk = gridDim.x;
    const int gsz = nblk * 256;
    const int gtid = bid * 256 + tid;
    const int2* e2 = reinterpret_cast<const int2*>(edge);
    __shared__ int red[256];
    __shared__ int sc[128];

    // phase 0: zero counts
    for (int i = gtid; i < N_NODES; i += gsz) counts[i] = 0;
    grid.sync();
    // phase 1: histogram
    for (int e = gtid; e < N_EDGES; e += gsz) atomicAdd(&counts[e2[e].y], 1);
    grid.sync();
    // phase 2a: per-block chunk sums
    const int CH = (N_NODES + nblk - 1) / nblk;           // 98 @ 1024 blocks
    const int lo = bid * CH, hi = min(lo + CH, N_NODES);
    int s = 0;
    for (int i = lo + tid; i < hi; i += 256) s += counts[i];
    red[tid] = s;
    __syncthreads();
    for (int o = 128; o > 0; o >>= 1) {
        if (tid < o) red[tid] += red[tid + o];
        __syncthreads();
    }
    if (tid == 0) partial[bid] = red[0];
    grid.sync();
    // phase 2b: block 0 exclusive-scans partial[nblk]
    if (bid == 0) {
        const int PC = (nblk + 255) / 256;                // 4 @ 1024 blocks
        int vals[8];
        int ssum = 0;
        const int mylo = tid * PC;
#pragma unroll 4
        for (int j = 0; j < PC; ++j) {
            const int idx = mylo + j;
            const int v = (idx < nblk) ? partial[idx] : 0;
            vals[j] = ssum; ssum += v;
        }
        red[tid] = ssum;
        __syncthreads();
        for (int o = 1; o < 256; o <<= 1) {
            const int t2 = (tid >= o) ? red[tid - o] : 0;
            __syncthreads();
            red[tid] += t2;
            __syncthreads();
        }
        const int ebase = red[tid] - ssum;
#pragma unroll 4
        for (int j = 0; j < PC; ++j) {
            const int idx = mylo + j;
            if (idx < nblk) partial[idx] = ebase + vals[j];
        }
    }
    grid.sync();
    // phase 2c: per-block exclusive offsets within chunk (CH <= 128)
    {
        const int base = partial[bid];
        const int n = hi - lo;
        int v = 0;
        if (tid < n) v = counts[lo + tid];
        if (tid < 128) sc[tid] = v;
        __syncthreads();
        for (int o = 1; o < 128; o <<= 1) {
            int t2 = 0;
            if (tid >= o && tid < 128) t2 = sc[tid - o];
            __syncthreads();
            if (tid < 128) sc[tid] += t2;
            __syncthreads();
        }
        if (tid < n) offs[lo + tid] = base + sc[tid] - v;
    }
    grid.sync();
    // phase 3: scatter
    for (int e = gtid; e < N_EDGES; e += gsz) {
        const int2 sd = e2[e];
        const int pos = atomicAdd(&offs[sd.y], 1);
        sE[pos] = sd;
        sOrig[pos] = e;
    }
}

// ---------------- non-coop fallback sort chain (round-6 kernels) ----------------
__global__ __launch_bounds__(256) void zero_kernel(int* __restrict__ counts) {
    const int i = blockIdx.x * 256 + threadIdx.x;
    if (i < N_NODES) counts[i] = 0;
}
__global__ __launch_bounds__(256) void hist_kernel(const int* __restrict__ edge,
                                                   int* __restrict__ counts) {
    const int2* e2 = reinterpret_cast<const int2*>(edge);
    for (int e = blockIdx.x * 256 + threadIdx.x; e < N_EDGES; e += gridDim.x * 256)
        atomicAdd(&counts[e2[e].y], 1);
}
__global__ __launch_bounds__(1024) void scanA_kernel(const int* __restrict__ counts,
                                                     int* __restrict__ offs,
                                                     int* __restrict__ bsum) {
    __shared__ int buf[1024];
    const int tid = threadIdx.x;
    const int i = blockIdx.x * 1024 + tid;
    const int v = (i < N_NODES) ? counts[i] : 0;
    buf[tid] = v;
    __syncthreads();
    for (int off = 1; off < 1024; off <<= 1) {
        const int t = (tid >= off) ? buf[tid - off] : 0;
        __syncthreads();
        buf[tid] += t;
        __syncthreads();
    }
    if (i < N_NODES) offs[i] = buf[tid] - v;
    if (tid == 1023) bsum[blockIdx.x] = buf[1023];
}
__global__ __launch_bounds__(64) void scanB_kernel(int* __restrict__ bsum, int nblk) {
    const int lane = threadIdx.x;
    int carry = 0;
    for (int c0 = 0; c0 < nblk; c0 += 64) {
        const int i = c0 + lane;
        int v = (i < nblk) ? bsum[i] : 0;
        int s = v;
#pragma unroll
        for (int m = 1; m < 64; m <<= 1) {
            int t = __shfl_up(s, m, 64);
            if (lane >= m) s += t;
        }
        if (i < nblk) bsum[i] = carry + s - v;
        carry += __shfl(s, 63, 64);
    }
}
__global__ __launch_bounds__(1024) void scanC_kernel(int* __restrict__ offs,
                                                     const int* __restrict__ bsum) {
    const int i = blockIdx.x * 1024 + threadIdx.x;
    if (i < N_NODES) offs[i] += bsum[blockIdx.x];
}
__global__ __launch_bounds__(256) void scatter_kernel(const int* __restrict__ edge,
                                                      int* __restrict__ offs,
                                                      int2* __restrict__ sE,
                                                      int* __restrict__ sOrig) {
    const int2* e2 = reinterpret_cast<const int2*>(edge);
    for (int e = blockIdx.x * 256 + threadIdx.x; e < N_EDGES; e += gridDim.x * 256) {
        const int2 sd = e2[e];
        const int pos = atomicAdd(&offs[sd.y], 1);
        sE[pos] = sd;
        sOrig[pos] = e;
    }
}

// ---------------- main edge kernel (unchanged, measured 121us sorted) ----------------
__global__ __launch_bounds__(256) void edge_kernel(
    const int2* __restrict__ eArr, const int* __restrict__ orig,
    const _Float16* __restrict__ P,
    const float* __restrict__ w_h1, const float* __restrict__ b_h1,
    const float* __restrict__ w_h2, const float* __restrict__ b_h2,
    const float* __restrict__ w_c2, const float* __restrict__ b_c2,
    const float* __restrict__ b_b, const float* __restrict__ sw,
    float* __restrict__ out)
{
    __shared__ f16x8 bwlds[1024];   // W_h1 B-fragments: idx=(nt*4+kk)*64 + g*16 + r

    const int tid = threadIdx.x;
    for (int e = tid; e < 1024; e += 256) {
        const int r_ = e & 15, g_ = (e >> 4) & 3, kkf = (e >> 6) & 3, ntf = e >> 8;
        const float* wr = w_h1 + (size_t)(ntf * 16 + r_) * 128 + kkf * 32 + g_ * 8;
        float4 f0 = *reinterpret_cast<const float4*>(wr);
        float4 f1 = *reinterpret_cast<const float4*>(wr + 4);
        bwlds[e] = pack8(f0, f1);
    }
    __syncthreads();

    const int lane = tid & 63;
    const int r = lane & 15, g = lane >> 4;

    const float s0 = sw[0], s1 = sw[1], s2 = sw[2];
    const float mx = fmaxf(s0, fmaxf(s1, s2));
    const float e0 = __expf(s0 - mx), e1 = __expf(s1 - mx), e2 = __expf(s2 - mx);
    const float inv = 1.0f / (e0 + e1 + e2);
    const float W0 = e0 * inv, W1 = e1 * inv, W2 = e2 * inv;
    const float cbias = W0 * b_h2[0] + W1 * b_c2[0] + W2 * b_b[0];

    float bh1v[4], wh2v[4];
#pragma unroll
    for (int nt = 0; nt < 4; ++nt) {
        bh1v[nt] = b_h1[nt * 16 + r];
        wh2v[nt] = w_h2[nt * 16 + r] * W0;   // W0 folded
    }
    f16x8 wc2r[4];
#pragma unroll
    for (int kk = 0; kk < 4; ++kk) {
        const int k0 = kk * 32 + g * 8;
        float4 f0 = *reinterpret_cast<const float4*>(w_c2 + k0);
        float4 f1 = *reinterpret_cast<const float4*>(w_c2 + k0 + 4);
        f0.x *= W1; f0.y *= W1; f0.z *= W1; f0.w *= W1;
        f1.x *= W1; f1.y *= W1; f1.z *= W1; f1.w *= W1;
        wc2r[kk] = pack8(f0, f1);   // W1 folded
    }
    const f16x8* myb = bwlds + g * 16 + r;

    const int gwid = (blockIdx.x * blockDim.x + tid) >> 6;
    const int nW = (gridDim.x * blockDim.x) >> 6;
    const int per = (NB + nW - 1) / nW;
    const int b0 = gwid * per;
    const int b1 = min(b0 + per, NB);
    const int rsel = r & 3;
    const int srcl = ((r >> 2) << 4) | r;

    int b = b0;
    int2 sd = make_int2(0, 0);
    int ov = 0;
    if (b < b1) {
        sd = eArr[b * 16 + r];
        ov = orig ? orig[b * 16 + r] : b * 16 + r;
    }

    for (; b < b1; ++b) {
        int2 sdn = sd; int ovn = ov;
        if (b + 1 < b1) {
            sdn = eArr[(b + 1) * 16 + r];
            ovn = orig ? orig[(b + 1) * 16 + r] : (b + 1) * 16 + r;
        }

        const _Float16* ps = P + (size_t)sd.x * PROW;
        const _Float16* pd = P + (size_t)sd.y * PROW;

        f16x8 av[4], bv[4], yv[4], zs[4], zd[4];
#pragma unroll
        for (int kk = 0; kk < 4; ++kk) {
            const int off = kk * 32 + g * 8;
            av[kk] = *reinterpret_cast<const f16x8*>(ps + off);         // A'[src]
            bv[kk] = *reinterpret_cast<const f16x8*>(pd + 128 + off);   // B[dst]
            yv[kk] = *reinterpret_cast<const f16x8*>(pd + 256 + off);   // Y[dst]
            zs[kk] = *reinterpret_cast<const f16x8*>(ps + 384 + off);   // Zh[src]
            zd[kk] = *reinterpret_cast<const f16x8*>(pd + 384 + off);   // Zh[dst]
        }

        // score1 via MFMA
        f32x4 acc[4] = {};
#pragma unroll
        for (int kk = 0; kk < 4; ++kk) {
            f16x8 a = zs[kk] * zd[kk];
            mfma16(acc[0], a, myb[(0 * 4 + kk) * 64]);
            mfma16(acc[1], a, myb[(1 * 4 + kk) * 64]);
            mfma16(acc[2], a, myb[(2 * 4 + kk) * 64]);
            mfma16(acc[3], a, myb[(3 * 4 + kk) * 64]);
        }
        float t4[4];
#pragma unroll
        for (int rr = 0; rr < 4; ++rr) {
            float s = 0.f;
#pragma unroll
            for (int nt = 0; nt < 4; ++nt)
                s = fmaf(fmaxf(acc[nt][rr] + bh1v[nt], 0.f), wh2v[nt], s);
            t4[rr] = s;
        }
#pragma unroll
        for (int mask = 1; mask <= 8; mask <<= 1) {
#pragma unroll
            for (int rr = 0; rr < 4; ++rr)
                t4[rr] += __shfl_xor(t4[rr], mask, 16);
        }
        float u = t4[0];
        if (rsel == 1) u = t4[1];
        if (rsel == 2) u = t4[2];
        if (rsel == 3) u = t4[3];
        const float sc1w = __shfl(u, srcl, 64);

        // score2 & score3
        float sA = 0.f, sB = 0.f;
#pragma unroll
        for (int kk = 0; kk < 4; ++kk) {
            f16x8 s = av[kk] + bv[kk];
            s = __builtin_elementwise_max(s, (f16x8)(_Float16)0.f);
#pragma unroll
            for (int j2 = 0; j2 < 4; ++j2) {
                sA = fdot2(s, wc2r[kk], j2, sA);
                sB = fdot2(zs[kk], yv[kk], j2, sB);
            }
        }
        sA += __shfl_xor(sA, 16, 64);
        sA += __shfl_xor(sA, 32, 64);
        sB += __shfl_xor(sB, 16, 64);
        sB += __shfl_xor(sB, 32, 64);

        const float res = sc1w + sA + fmaf(W2, sB, cbias);
        if (lane < 16) out[ov] = res;
        sd = sdn; ov = ovn;
    }
}

// ---------------- fallback: fused wave-per-edge, no workspace ----------------
__global__ __launch_bounds__(256) void fused_fallback(
    const float* __restrict__ z, const int* __restrict__ edge,
    const float* __restrict__ w_h1, const float* __restrict__ b_h1,
    const float* __restrict__ w_h2, const float* __restrict__ b_h2,
    const float* __restrict__ w_c1, const float* __restrict__ b_c1,
    const float* __restrict__ w_c2, const float* __restrict__ b_c2,
    const float* __restrict__ w_b, const float* __restrict__ b_b,
    const float* __restrict__ sw, float* __restrict__ out)
{
    __shared__ float zbuf[4][256];
    const int lane = threadIdx.x & 63;
    const int w = threadIdx.x >> 6;
    const int gw = blockIdx.x * 4 + w;
    const int nw = gridDim.x * 4;

    const float s0 = sw[0], s1 = sw[1], s2 = sw[2];
    const float mx = fmaxf(s0, fmaxf(s1, s2));
    const float e0 = __expf(s0 - mx), e1 = __expf(s1 - mx), e2 = __expf(s2 - mx);
    const float inv = 1.0f / (e0 + e1 + e2);
    const float W0 = e0 * inv, W1 = e1 * inv, W2 = e2 * inv;
    const float cbias = W0 * b_h2[0] + W1 * b_c2[0] + W2 * b_b[0];

    for (int e = gw; e < N_EDGES; e += nw) {
        const int src = edge[2 * e], dst = edge[2 * e + 1];
        const float zs0 = z[(size_t)src * 128 + lane];
        const float zs1 = z[(size_t)src * 128 + 64 + lane];
        const float zd0 = z[(size_t)dst * 128 + lane];
        const float zd1 = z[(size_t)dst * 128 + 64 + lane];
        zbuf[w][lane] = zs0; zbuf[w][64 + lane] = zs1;
        zbuf[w][128 + lane] = zd0; zbuf[w][192 + lane] = zd1;
        asm volatile("s_waitcnt lgkmcnt(0)" ::: "memory");

        float h = 0.f;
        const float* whr = w_h1 + (size_t)lane * 128;
        for (int d = 0; d < 128; ++d)
            h = fmaf(zbuf[w][d] * zbuf[w][128 + d], whr[d], h);
        float sc1 = fmaxf(h + b_h1[lane], 0.f) * w_h2[lane];

        float c0 = 0.f, c1 = 0.f;
        const float* w0r = w_c1 + (size_t)lane * 256;
        const float* w1r = w_c1 + (size_t)(lane + 64) * 256;
        for (int d = 0; d < 256; ++d) {
            const float cat = zbuf[w][d];
            c0 = fmaf(cat, w0r[d], c0);
            c1 = fmaf(cat, w1r[d], c1);
        }
        float sc2 = fmaxf(c0 + b_c1[lane], 0.f) * w_c2[lane]
                  + fmaxf(c1 + b_c1[lane + 64], 0.f) * w_c2[lane + 64];

        float t0 = 0.f, t1 = 0.f;
        const float* wb0 = w_b + (size_t)lane * 128;
        const float* wb1 = w_b + (size_t)(lane + 64) * 128;
        for (int f = 0; f < 128; ++f) {
            const float zdf = zbuf[w][128 + f];
            t0 = fmaf(wb0[f], zdf, t0);
            t1 = fmaf(wb1[f], zdf, t1);
        }
        float sc3 = zs0 * t0 + zs1 * t1;

        float v = fmaf(W0, sc1, fmaf(W1, sc2, W2 * sc3));
#pragma unroll
        for (int m = 1; m < 64; m <<= 1) v += __shfl_xor(v, m, 64);
        if (lane == 0) out[e] = v + cbias;
    }
}

extern "C" void kernel_launch(void* const* d_in, const int* in_sizes, int n_in,
                              void* d_out, int out_size, void* d_ws, size_t ws_size,
                              hipStream_t stream)
{
    const float* z    = (const float*)d_in[0];
    const int*   edge = (const int*)d_in[1];
    const float* w_h1 = (const float*)d_in[2];
    const float* b_h1 = (const float*)d_in[3];
    const float* w_h2 = (const float*)d_in[4];
    const float* b_h2 = (const float*)d_in[5];
    const float* w_c1 = (const float*)d_in[6];
    const float* b_c1 = (const float*)d_in[7];
    const float* w_c2 = (const float*)d_in[8];
    const float* b_c2 = (const float*)d_in[9];
    const float* w_b  = (const float*)d_in[10];
    const float* b_b  = (const float*)d_in[11];
    const float* sw   = (const float*)d_in[12];
    float* outp = (float*)d_out;

    // ws layout
    const size_t szP    = (size_t)N_NODES * PROW * sizeof(_Float16);  // 102,400,000
    const size_t szCnt  = (size_t)N_NODES * sizeof(int);              //     400,000
    const size_t szPar  = 8192;                                       // 1024+ ints
    const size_t szSE   = (size_t)N_EDGES * sizeof(int2);             //   8,000,000
    const size_t szSO   = (size_t)N_EDGES * sizeof(int);              //   4,000,000
    const size_t needP    = szP;
    const size_t needSort = szP + 2 * szCnt + szPar + szSE + szSO;    // ~115.2 MB

    if (ws_size >= needP) {
        char* wsb = (char*)d_ws;
        _Float16* P = (_Float16*)wsb;
        hipLaunchKernelGGL(precomp_kernel, dim3(768), dim3(256), 0, stream,
                           z, w_c1, b_c1, w_b, P);
        hipLaunchKernelGGL(zb_kernel, dim3((N_NODES * 16 + 255) / 256), dim3(256),
                           0, stream, z, P);
        if (ws_size >= needSort) {
            int*  counts = (int*)(wsb + szP);
            int*  offs   = (int*)(wsb + szP + szCnt);
            int*  partial= (int*)(wsb + szP + 2 * szCnt);
            int2* sE     = (int2*)(wsb + szP + 2 * szCnt + szPar);
            int*  sOrig  = (int*)(wsb + szP + 2 * szCnt + szPar + szSE);

            void* args[] = { (void*)&edge, (void*)&counts, (void*)&offs,
                             (void*)&partial, (void*)&sE, (void*)&sOrig };
            hipError_t cerr = hipLaunchCooperativeKernel(
                (const void*)sort_kernel, dim3(1024), dim3(256), args, 0, stream);
            if (cerr != hipSuccess) {
                // non-coop fallback chain
                const int nblk = (N_NODES + 1023) / 1024;   // 98
                hipLaunchKernelGGL(zero_kernel, dim3((N_NODES + 255) / 256), dim3(256),
                                   0, stream, counts);
                hipLaunchKernelGGL(hist_kernel, dim3(1024), dim3(256), 0, stream,
                                   edge, counts);
                hipLaunchKernelGGL(scanA_kernel, dim3(nblk), dim3(1024), 0, stream,
                                   counts, offs, partial);
                hipLaunchKernelGGL(scanB_kernel, dim3(1), dim3(64), 0, stream,
                                   partial, nblk);
                hipLaunchKernelGGL(scanC_kernel, dim3(nblk), dim3(1024), 0, stream,
                                   offs, partial);
                hipLaunchKernelGGL(scatter_kernel, dim3(1024), dim3(256), 0, stream,
                                   edge, offs, sE, sOrig);
            }
            hipLaunchKernelGGL(edge_kernel, dim3(1024), dim3(256), 0, stream,
                               sE, sOrig, P, w_h1, b_h1, w_h2, b_h2, w_c2, b_c2,
                               b_b, sw, outp);
        } else {
            hipLaunchKernelGGL(edge_kernel, dim3(1024), dim3(256), 0, stream,
                               (const int2*)edge, (const int*)nullptr, P,
                               w_h1, b_h1, w_h2, b_h2, w_c2, b_c2, b_b, sw, outp);
        }
    } else {
        hipLaunchKernelGGL(fused_fallback, dim3(4096), dim3(256), 0, stream,
                           z, edge, w_h1, b_h1, w_h2, b_h2, w_c1, b_c1,
                           w_c2, b_c2, w_b, b_b, sw, outp);
    }
}

// Round 9
// 239.161 us; speedup vs baseline: 3.2086x; 3.2086x over previous
//
#include <hip/hip_runtime.h>
#include <hip/hip_bf16.h>

#define N_NODES 100000
#define N_EDGES 1000000
// SoA node tables in d_ws:
//   P_src[node] (384B): [A' fp8e4m3 x128 | Zh f16 x128]   (A' = Wc1a@z + b_c1)
//   P_dst[node] (640B): [B  fp8e4m3 x128 | Y f16 x128 | Zh f16 x128]
//     B = Wc1b@z (no bias; bias folded into A'), Y = Wb@z
#define SRCB 384
#define DSTB 640
#define NB (N_EDGES / 16)       // 62500

typedef float f32x4 __attribute__((ext_vector_type(4)));
typedef float f32x2 __attribute__((ext_vector_type(2)));
typedef _Float16 f16x8 __attribute__((ext_vector_type(8)));
typedef _Float16 f16x2 __attribute__((ext_vector_type(2)));

__device__ inline f16x8 pack8(float4 a, float4 b) {
    f16x8 o;
    o[0] = (_Float16)a.x; o[1] = (_Float16)a.y; o[2] = (_Float16)a.z; o[3] = (_Float16)a.w;
    o[4] = (_Float16)b.x; o[5] = (_Float16)b.y; o[6] = (_Float16)b.z; o[7] = (_Float16)b.w;
    return o;
}
__device__ inline void mfma16(f32x4& acc, f16x8 a, f16x8 b) {
    acc = __builtin_amdgcn_mfma_f32_16x16x32_f16(a, b, acc, 0, 0, 0);
}
__device__ inline float fdot2(f16x8 a, f16x8 b, int j2, float c) {
    f16x2 pa = { a[2 * j2], a[2 * j2 + 1] };
    f16x2 pb = { b[2 * j2], b[2 * j2 + 1] };
    return __builtin_amdgcn_fdot2(pa, pb, c, false);
}
__device__ inline unsigned char f2fp8(float v) {
    // v_cvt_pk_fp8_f32 packs 2 fp8 into low word; take byte 0 (OCP e4m3 on gfx950)
    int p = __builtin_amdgcn_cvt_pk_fp8_f32(v, v, 0, false);
    return (unsigned char)(p & 0xff);
}

// ---- precompute (round-2 measured structure): GEMM cols 0..383 over 6 col-tiles ----
// ct 0-1 -> A' (fp8, P_src, +b_c1) ; ct 2-3 -> B (fp8, P_dst) ; ct 4-5 -> Y (f16, P_dst)
__global__ __launch_bounds__(256) void precomp_kernel(
    const float* __restrict__ z, const float* __restrict__ w_c1,
    const float* __restrict__ b_c1, const float* __restrict__ w_b,
    unsigned char* __restrict__ Ps8, unsigned char* __restrict__ Pd8)
{
    const int lane = threadIdx.x & 63;
    const int r = lane & 15, g = lane >> 4;
    const int wid = blockIdx.x * 4 + (threadIdx.x >> 6);
    const int ct = wid % 6;          // 6 col-tiles of 64 over 384 output cols
    const int walker = wid / 6;
    const int nWalk = (gridDim.x * 4) / 6;
    if (walker >= nWalk) return;

    f16x8 bw[4][4];                  // B-fragments, loaded once
#pragma unroll
    for (int nt = 0; nt < 4; ++nt) {
        const int c = ct * 64 + nt * 16 + r;
        const float* wrow;
        if (c < 128)       wrow = w_c1 + (size_t)c * 256;               // Wc1a row
        else if (c < 256)  wrow = w_c1 + (size_t)(c - 128) * 256 + 128; // Wc1b row
        else               wrow = w_b + (size_t)(c - 256) * 128;        // Wb row
#pragma unroll
        for (int kk = 0; kk < 4; ++kk) {
            const int k0 = kk * 32 + g * 8;
            float4 f0 = *reinterpret_cast<const float4*>(wrow + k0);
            float4 f1 = *reinterpret_cast<const float4*>(wrow + k0 + 4);
            bw[nt][kk] = pack8(f0, f1);
        }
    }
    float bc1v[4] = {0.f, 0.f, 0.f, 0.f};
    if (ct < 2) {
#pragma unroll
        for (int nt = 0; nt < 4; ++nt) bc1v[nt] = b_c1[ct * 64 + nt * 16 + r];
    }

    for (int nb = walker; nb < N_NODES / 16; nb += nWalk) {
        const float* zp = z + (size_t)(nb * 16 + r) * 128;
        f32x4 acc[4] = {};
#pragma unroll
        for (int kk = 0; kk < 4; ++kk) {
            const int k0 = kk * 32 + g * 8;
            float4 z0 = *reinterpret_cast<const float4*>(zp + k0);
            float4 z1 = *reinterpret_cast<const float4*>(zp + k0 + 4);
            f16x8 a = pack8(z0, z1);
#pragma unroll
            for (int nt = 0; nt < 4; ++nt) mfma16(acc[nt], a, bw[nt][kk]);
        }
#pragma unroll
        for (int nt = 0; nt < 4; ++nt) {
#pragma unroll
            for (int rr = 0; rr < 4; ++rr) {
                const float v = acc[nt][rr] + bc1v[nt];
                const int node = nb * 16 + g * 4 + rr;
                const int c = ct * 64 + nt * 16 + r;
                if (ct < 2) {
                    Ps8[(size_t)node * SRCB + c] = f2fp8(v);                  // A'
                } else if (ct < 4) {
                    Pd8[(size_t)node * DSTB + (c - 128)] = f2fp8(v);          // B
                } else {
                    *reinterpret_cast<_Float16*>(
                        Pd8 + (size_t)node * DSTB + 128 + (size_t)(c - 256) * 2)
                        = (_Float16)v;                                        // Y
                }
            }
        }
    }
}

// ---- Zh: f16 copy of z into BOTH P_src[128..383] and P_dst[384..639] ----
__global__ __launch_bounds__(256) void zb_kernel(const float* __restrict__ z,
                                                 unsigned char* __restrict__ Ps8,
                                                 unsigned char* __restrict__ Pd8)
{
    const int i = blockIdx.x * 256 + threadIdx.x;
    if (i >= N_NODES * 16) return;
    const int node = i >> 4, ch = i & 15;
    const float* zp = z + (size_t)node * 128 + ch * 8;
    float4 a = *reinterpret_cast<const float4*>(zp);
    float4 b = *reinterpret_cast<const float4*>(zp + 4);
    f16x8 h = pack8(a, b);
    *reinterpret_cast<f16x8*>(Ps8 + (size_t)node * SRCB + 128 + ch * 16) = h;
    *reinterpret_cast<f16x8*>(Pd8 + (size_t)node * DSTB + 384 + ch * 16) = h;
}

// ---- main edge kernel: 16 edges/wave, unified lane layout, unsorted, fp8 A'/B ----
// lane = g*16 + r : edge = b*16 + r, k-slice = {kk*32 + g*8 .. +8} for kk=0..3
__global__ __launch_bounds__(256) void edge_kernel(
    const int2* __restrict__ edge2,
    const unsigned char* __restrict__ Ps8, const unsigned char* __restrict__ Pd8,
    const float* __restrict__ w_h1, const float* __restrict__ b_h1,
    const float* __restrict__ w_h2, const float* __restrict__ b_h2,
    const float* __restrict__ w_c2, const float* __restrict__ b_c2,
    const float* __restrict__ b_b, const float* __restrict__ sw,
    float* __restrict__ out)
{
    __shared__ f16x8 bwlds[1024];   // W_h1 B-fragments: idx=(nt*4+kk)*64 + g*16 + r

    const int tid = threadIdx.x;
    for (int e = tid; e < 1024; e += 256) {
        const int r_ = e & 15, g_ = (e >> 4) & 3, kkf = (e >> 6) & 3, ntf = e >> 8;
        const float* wr = w_h1 + (size_t)(ntf * 16 + r_) * 128 + kkf * 32 + g_ * 8;
        float4 f0 = *reinterpret_cast<const float4*>(wr);
        float4 f1 = *reinterpret_cast<const float4*>(wr + 4);
        bwlds[e] = pack8(f0, f1);
    }
    __syncthreads();

    const int lane = tid & 63;
    const int r = lane & 15, g = lane >> 4;

    const float s0 = sw[0], s1 = sw[1], s2 = sw[2];
    const float mx = fmaxf(s0, fmaxf(s1, s2));
    const float e0 = __expf(s0 - mx), e1 = __expf(s1 - mx), e2 = __expf(s2 - mx);
    const float inv = 1.0f / (e0 + e1 + e2);
    const float W0 = e0 * inv, W1 = e1 * inv, W2 = e2 * inv;
    const float cbias = W0 * b_h2[0] + W1 * b_c2[0] + W2 * b_b[0];

    float bh1v[4], wh2v[4];
#pragma unroll
    for (int nt = 0; nt < 4; ++nt) {
        bh1v[nt] = b_h1[nt * 16 + r];
        wh2v[nt] = w_h2[nt * 16 + r] * W0;   // W0 folded
    }
    f16x8 wc2r[4];
#pragma unroll
    for (int kk = 0; kk < 4; ++kk) {
        const int k0 = kk * 32 + g * 8;
        float4 f0 = *reinterpret_cast<const float4*>(w_c2 + k0);
        float4 f1 = *reinterpret_cast<const float4*>(w_c2 + k0 + 4);
        f0.x *= W1; f0.y *= W1; f0.z *= W1; f0.w *= W1;
        f1.x *= W1; f1.y *= W1; f1.z *= W1; f1.w *= W1;
        wc2r[kk] = pack8(f0, f1);   // W1 folded
    }
    const f16x8* myb = bwlds + g * 16 + r;

    const int gwid = (blockIdx.x * blockDim.x + tid) >> 6;
    const int nW = (gridDim.x * blockDim.x) >> 6;
    const int rsel = r & 3;
    const int srcl = ((r >> 2) << 4) | r;

    int b = gwid;
    int2 sd = make_int2(0, 0);
    if (b < NB) sd = edge2[b * 16 + r];

    for (; b < NB; b += nW) {
        const int bn = b + nW;
        int2 sdn = sd;
        if (bn < NB) sdn = edge2[bn * 16 + r];   // prefetch next iter's indices

        const int base = b * 16;
        const unsigned char* ps = Ps8 + (size_t)sd.x * SRCB;
        const unsigned char* pd = Pd8 + (size_t)sd.y * DSTB;

        // ---- issue all gathers up front (2 bases, static offsets) ----
        uint2 a8[4], b8[4];
        f16x8 zs[4], yv[4], zd[4];
#pragma unroll
        for (int kk = 0; kk < 4; ++kk) {
            const int o8 = kk * 32 + g * 8;
            a8[kk] = *reinterpret_cast<const uint2*>(ps + o8);               // A' fp8
            zs[kk] = *reinterpret_cast<const f16x8*>(ps + 128 + 2 * o8);     // Zh[src]
            b8[kk] = *reinterpret_cast<const uint2*>(pd + o8);               // B fp8
            yv[kk] = *reinterpret_cast<const f16x8*>(pd + 128 + 2 * o8);     // Y[dst]
            zd[kk] = *reinterpret_cast<const f16x8*>(pd + 384 + 2 * o8);     // Zh[dst]
        }

        // ---- score1: H(16x64) = (zs .* zd) @ Wh1^T via MFMA ----
        f32x4 acc[4] = {};
#pragma unroll
        for (int kk = 0; kk < 4; ++kk) {
            f16x8 a = zs[kk] * zd[kk];
            mfma16(acc[0], a, myb[(0 * 4 + kk) * 64]);
            mfma16(acc[1], a, myb[(1 * 4 + kk) * 64]);
            mfma16(acc[2], a, myb[(2 * 4 + kk) * 64]);
            mfma16(acc[3], a, myb[(3 * 4 + kk) * 64]);
        }
        float t4[4];
#pragma unroll
        for (int rr = 0; rr < 4; ++rr) {
            float s = 0.f;
#pragma unroll
            for (int nt = 0; nt < 4; ++nt)
                s = fmaf(fmaxf(acc[nt][rr] + bh1v[nt], 0.f), wh2v[nt], s);
            t4[rr] = s;
        }
#pragma unroll
        for (int mask = 1; mask <= 8; mask <<= 1) {
#pragma unroll
            for (int rr = 0; rr < 4; ++rr)
                t4[rr] += __shfl_xor(t4[rr], mask, 16);
        }
        float u = t4[0];
        if (rsel == 1) u = t4[1];
        if (rsel == 2) u = t4[2];
        if (rsel == 3) u = t4[3];
        const float sc1w = __shfl(u, srcl, 64);  // W0-folded score1 of edge base+lane%16

        // ---- score2 (fp8 A'+B, f32 relu, f16-folded wc2) & score3 ----
        float sA = 0.f, sB = 0.f;
#pragma unroll
        for (int kk = 0; kk < 4; ++kk) {
            f32x2 pa0 = __builtin_amdgcn_cvt_pk_f32_fp8((int)a8[kk].x, false);
            f32x2 pa1 = __builtin_amdgcn_cvt_pk_f32_fp8((int)a8[kk].x, true);
            f32x2 pa2 = __builtin_amdgcn_cvt_pk_f32_fp8((int)a8[kk].y, false);
            f32x2 pa3 = __builtin_amdgcn_cvt_pk_f32_fp8((int)a8[kk].y, true);
            f32x2 pb0 = __builtin_amdgcn_cvt_pk_f32_fp8((int)b8[kk].x, false);
            f32x2 pb1 = __builtin_amdgcn_cvt_pk_f32_fp8((int)b8[kk].x, true);
            f32x2 pb2 = __builtin_amdgcn_cvt_pk_f32_fp8((int)b8[kk].y, false);
            f32x2 pb3 = __builtin_amdgcn_cvt_pk_f32_fp8((int)b8[kk].y, true);
            float rl[8];
            rl[0] = fmaxf(pa0.x + pb0.x, 0.f); rl[1] = fmaxf(pa0.y + pb0.y, 0.f);
            rl[2] = fmaxf(pa1.x + pb1.x, 0.f); rl[3] = fmaxf(pa1.y + pb1.y, 0.f);
            rl[4] = fmaxf(pa2.x + pb2.x, 0.f); rl[5] = fmaxf(pa2.y + pb2.y, 0.f);
            rl[6] = fmaxf(pa3.x + pb3.x, 0.f); rl[7] = fmaxf(pa3.y + pb3.y, 0.f);
#pragma unroll
            for (int j = 0; j < 8; ++j)
                sA = fmaf(rl[j], (float)wc2r[kk][j], sA);
#pragma unroll
            for (int j2 = 0; j2 < 4; ++j2)
                sB = fdot2(zs[kk], yv[kk], j2, sB);
        }
        sA += __shfl_xor(sA, 16, 64);
        sA += __shfl_xor(sA, 32, 64);
        sB += __shfl_xor(sB, 16, 64);
        sB += __shfl_xor(sB, 32, 64);

        const float res = sc1w + sA + fmaf(W2, sB, cbias);
        if (lane < 16) out[base + lane] = res;
        sd = sdn;
    }
}

// ---------------- fallback: fused wave-per-edge, no workspace ----------------
__global__ __launch_bounds__(256) void fused_fallback(
    const float* __restrict__ z, const int* __restrict__ edge,
    const float* __restrict__ w_h1, const float* __restrict__ b_h1,
    const float* __restrict__ w_h2, const float* __restrict__ b_h2,
    const float* __restrict__ w_c1, const float* __restrict__ b_c1,
    const float* __restrict__ w_c2, const float* __restrict__ b_c2,
    const float* __restrict__ w_b, const float* __restrict__ b_b,
    const float* __restrict__ sw, float* __restrict__ out)
{
    __shared__ float zbuf[4][256];
    const int lane = threadIdx.x & 63;
    const int w = threadIdx.x >> 6;
    const int gw = blockIdx.x * 4 + w;
    const int nw = gridDim.x * 4;

    const float s0 = sw[0], s1 = sw[1], s2 = sw[2];
    const float mx = fmaxf(s0, fmaxf(s1, s2));
    const float e0 = __expf(s0 - mx), e1 = __expf(s1 - mx), e2 = __expf(s2 - mx);
    const float inv = 1.0f / (e0 + e1 + e2);
    const float W0 = e0 * inv, W1 = e1 * inv, W2 = e2 * inv;
    const float cbias = W0 * b_h2[0] + W1 * b_c2[0] + W2 * b_b[0];

    for (int e = gw; e < N_EDGES; e += nw) {
        const int src = edge[2 * e], dst = edge[2 * e + 1];
        const float zs0 = z[(size_t)src * 128 + lane];
        const float zs1 = z[(size_t)src * 128 + 64 + lane];
        const float zd0 = z[(size_t)dst * 128 + lane];
        const float zd1 = z[(size_t)dst * 128 + 64 + lane];
        zbuf[w][lane] = zs0; zbuf[w][64 + lane] = zs1;
        zbuf[w][128 + lane] = zd0; zbuf[w][192 + lane] = zd1;
        asm volatile("s_waitcnt lgkmcnt(0)" ::: "memory");

        float h = 0.f;
        const float* whr = w_h1 + (size_t)lane * 128;
        for (int d = 0; d < 128; ++d)
            h = fmaf(zbuf[w][d] * zbuf[w][128 + d], whr[d], h);
        float sc1 = fmaxf(h + b_h1[lane], 0.f) * w_h2[lane];

        float c0 = 0.f, c1 = 0.f;
        const float* w0r = w_c1 + (size_t)lane * 256;
        const float* w1r = w_c1 + (size_t)(lane + 64) * 256;
        for (int d = 0; d < 256; ++d) {
            const float cat = zbuf[w][d];
            c0 = fmaf(cat, w0r[d], c0);
            c1 = fmaf(cat, w1r[d], c1);
        }
        float sc2 = fmaxf(c0 + b_c1[lane], 0.f) * w_c2[lane]
                  + fmaxf(c1 + b_c1[lane + 64], 0.f) * w_c2[lane + 64];

        float t0 = 0.f, t1 = 0.f;
        const float* wb0 = w_b + (size_t)lane * 128;
        const float* wb1 = w_b + (size_t)(lane + 64) * 128;
        for (int f = 0; f < 128; ++f) {
            const float zdf = zbuf[w][128 + f];
            t0 = fmaf(wb0[f], zdf, t0);
            t1 = fmaf(wb1[f], zdf, t1);
        }
        float sc3 = zs0 * t0 + zs1 * t1;

        float v = fmaf(W0, sc1, fmaf(W1, sc2, W2 * sc3));
#pragma unroll
        for (int m = 1; m < 64; m <<= 1) v += __shfl_xor(v, m, 64);
        if (lane == 0) out[e] = v + cbias;
    }
}

extern "C" void kernel_launch(void* const* d_in, const int* in_sizes, int n_in,
                              void* d_out, int out_size, void* d_ws, size_t ws_size,
                              hipStream_t stream)
{
    const float* z    = (const float*)d_in[0];
    const int*   edge = (const int*)d_in[1];
    const float* w_h1 = (const float*)d_in[2];
    const float* b_h1 = (const float*)d_in[3];
    const float* w_h2 = (const float*)d_in[4];
    const float* b_h2 = (const float*)d_in[5];
    const float* w_c1 = (const float*)d_in[6];
    const float* b_c1 = (const float*)d_in[7];
    const float* w_c2 = (const float*)d_in[8];
    const float* b_c2 = (const float*)d_in[9];
    const float* w_b  = (const float*)d_in[10];
    const float* b_b  = (const float*)d_in[11];
    const float* sw   = (const float*)d_in[12];
    float* outp = (float*)d_out;

    const size_t szSrc = (size_t)N_NODES * SRCB;   // 38,400,000
    const size_t szDst = (size_t)N_NODES * DSTB;   // 64,000,000
    const size_t need  = szSrc + szDst;            // 102.4 MB (known to fit)

    if (ws_size >= need) {
        unsigned char* Ps8 = (unsigned char*)d_ws;
        unsigned char* Pd8 = (unsigned char*)d_ws + szSrc;
        hipLaunchKernelGGL(precomp_kernel, dim3(768), dim3(256), 0, stream,
                           z, w_c1, b_c1, w_b, Ps8, Pd8);
        hipLaunchKernelGGL(zb_kernel, dim3((N_NODES * 16 + 255) / 256), dim3(256),
                           0, stream, z, Ps8, Pd8);
        // ~120 VGPR -> 4 blocks/CU co-resident; 256 CU * 4 = 1024 (no tail)
        hipLaunchKernelGGL(edge_kernel, dim3(1024), dim3(256), 0, stream,
                           (const int2*)edge, Ps8, Pd8, w_h1, b_h1, w_h2, b_h2,
                           w_c2, b_c2, b_b, sw, outp);
    } else {
        hipLaunchKernelGGL(fused_fallback, dim3(4096), dim3(256), 0, stream,
                           z, edge, w_h1, b_h1, w_h2, b_h2, w_c1, b_c1,
                           w_c2, b_c2, w_b, b_b, sw, outp);
    }
}

// Round 10
// 225.147 us; speedup vs baseline: 3.4084x; 1.0622x over previous
//
#include <hip/hip_runtime.h>
#include <hip/hip_bf16.h>

#define N_NODES 100000
#define N_EDGES 1000000
// SoA node tables in d_ws:
//   P_src[node] (384B): [A' fp8e4m3 x128 | Zh f16 x128]   (A' = Wc1a@z + b_c1)
//   P_dst[node] (640B): [B  fp8e4m3 x128 | Y f16 x128 | Zh f16 x128]
//     B = Wc1b@z (no bias; bias folded into A'), Y = Wb@z
// Edge-kernel k-map (lane g, mfma kk, elem j): k = g*32 + kk*8 + j
//   -> per-lane contiguous runs: A'/B 32B, Zh/Y 64B (all 16B loads)
#define SRCB 384
#define DSTB 640
#define NB (N_EDGES / 16)       // 62500

typedef float f32x4 __attribute__((ext_vector_type(4)));
typedef float f32x2 __attribute__((ext_vector_type(2)));
typedef _Float16 f16x8 __attribute__((ext_vector_type(8)));
typedef _Float16 f16x2 __attribute__((ext_vector_type(2)));

__device__ inline f16x8 pack8(float4 a, float4 b) {
    f16x8 o;
    o[0] = (_Float16)a.x; o[1] = (_Float16)a.y; o[2] = (_Float16)a.z; o[3] = (_Float16)a.w;
    o[4] = (_Float16)b.x; o[5] = (_Float16)b.y; o[6] = (_Float16)b.z; o[7] = (_Float16)b.w;
    return o;
}
__device__ inline void mfma16(f32x4& acc, f16x8 a, f16x8 b) {
    acc = __builtin_amdgcn_mfma_f32_16x16x32_f16(a, b, acc, 0, 0, 0);
}
__device__ inline float fdot2(f16x8 a, f16x8 b, int j2, float c) {
    f16x2 pa = { a[2 * j2], a[2 * j2 + 1] };
    f16x2 pb = { b[2 * j2], b[2 * j2 + 1] };
    return __builtin_amdgcn_fdot2(pa, pb, c, false);
}
__device__ inline unsigned char f2fp8(float v) {
    int p = __builtin_amdgcn_cvt_pk_fp8_f32(v, v, 0, false);
    return (unsigned char)(p & 0xff);
}

// ---- precompute (round-2 measured structure): GEMM cols 0..383 over 6 col-tiles ----
// ct 0-1 -> A' (fp8, P_src, +b_c1) ; ct 2-3 -> B (fp8, P_dst) ; ct 4-5 -> Y (f16, P_dst)
__global__ __launch_bounds__(256) void precomp_kernel(
    const float* __restrict__ z, const float* __restrict__ w_c1,
    const float* __restrict__ b_c1, const float* __restrict__ w_b,
    unsigned char* __restrict__ Ps8, unsigned char* __restrict__ Pd8)
{
    const int lane = threadIdx.x & 63;
    const int r = lane & 15, g = lane >> 4;
    const int wid = blockIdx.x * 4 + (threadIdx.x >> 6);
    const int ct = wid % 6;          // 6 col-tiles of 64 over 384 output cols
    const int walker = wid / 6;
    const int nWalk = (gridDim.x * 4) / 6;
    if (walker >= nWalk) return;

    f16x8 bw[4][4];                  // B-fragments, loaded once
#pragma unroll
    for (int nt = 0; nt < 4; ++nt) {
        const int c = ct * 64 + nt * 16 + r;
        const float* wrow;
        if (c < 128)       wrow = w_c1 + (size_t)c * 256;               // Wc1a row
        else if (c < 256)  wrow = w_c1 + (size_t)(c - 128) * 256 + 128; // Wc1b row
        else               wrow = w_b + (size_t)(c - 256) * 128;        // Wb row
#pragma unroll
        for (int kk = 0; kk < 4; ++kk) {
            const int k0 = kk * 32 + g * 8;
            float4 f0 = *reinterpret_cast<const float4*>(wrow + k0);
            float4 f1 = *reinterpret_cast<const float4*>(wrow + k0 + 4);
            bw[nt][kk] = pack8(f0, f1);
        }
    }
    float bc1v[4] = {0.f, 0.f, 0.f, 0.f};
    if (ct < 2) {
#pragma unroll
        for (int nt = 0; nt < 4; ++nt) bc1v[nt] = b_c1[ct * 64 + nt * 16 + r];
    }

    for (int nb = walker; nb < N_NODES / 16; nb += nWalk) {
        const float* zp = z + (size_t)(nb * 16 + r) * 128;
        f32x4 acc[4] = {};
#pragma unroll
        for (int kk = 0; kk < 4; ++kk) {
            const int k0 = kk * 32 + g * 8;
            float4 z0 = *reinterpret_cast<const float4*>(zp + k0);
            float4 z1 = *reinterpret_cast<const float4*>(zp + k0 + 4);
            f16x8 a = pack8(z0, z1);
#pragma unroll
            for (int nt = 0; nt < 4; ++nt) mfma16(acc[nt], a, bw[nt][kk]);
        }
#pragma unroll
        for (int nt = 0; nt < 4; ++nt) {
#pragma unroll
            for (int rr = 0; rr < 4; ++rr) {
                const float v = acc[nt][rr] + bc1v[nt];
                const int node = nb * 16 + g * 4 + rr;
                const int c = ct * 64 + nt * 16 + r;
                if (ct < 2) {
                    Ps8[(size_t)node * SRCB + c] = f2fp8(v);                  // A'
                } else if (ct < 4) {
                    Pd8[(size_t)node * DSTB + (c - 128)] = f2fp8(v);          // B
                } else {
                    *reinterpret_cast<_Float16*>(
                        Pd8 + (size_t)node * DSTB + 128 + (size_t)(c - 256) * 2)
                        = (_Float16)v;                                        // Y
                }
            }
        }
    }
}

// ---- Zh: f16 copy of z into BOTH P_src[128..383] and P_dst[384..639] ----
__global__ __launch_bounds__(256) void zb_kernel(const float* __restrict__ z,
                                                 unsigned char* __restrict__ Ps8,
                                                 unsigned char* __restrict__ Pd8)
{
    const int i = blockIdx.x * 256 + threadIdx.x;
    if (i >= N_NODES * 16) return;
    const int node = i >> 4, ch = i & 15;
    const float* zp = z + (size_t)node * 128 + ch * 8;
    float4 a = *reinterpret_cast<const float4*>(zp);
    float4 b = *reinterpret_cast<const float4*>(zp + 4);
    f16x8 h = pack8(a, b);
    *reinterpret_cast<f16x8*>(Ps8 + (size_t)node * SRCB + 128 + ch * 16) = h;
    *reinterpret_cast<f16x8*>(Pd8 + (size_t)node * DSTB + 384 + ch * 16) = h;
}

// ---- main edge kernel: 16 edges/wave, remapped k for all-16B contiguous loads ----
// lane = g*16 + r : edge = b*16 + r; k(kk,g,j) = g*32 + kk*8 + j
__global__ __launch_bounds__(256) void edge_kernel(
    const int2* __restrict__ edge2,
    const unsigned char* __restrict__ Ps8, const unsigned char* __restrict__ Pd8,
    const float* __restrict__ w_h1, const float* __restrict__ b_h1,
    const float* __restrict__ w_h2, const float* __restrict__ b_h2,
    const float* __restrict__ w_c2, const float* __restrict__ b_c2,
    const float* __restrict__ b_b, const float* __restrict__ sw,
    float* __restrict__ out)
{
    __shared__ f16x8 bwlds[1024];   // entry (nt,kk,g,r): w_h1[nt*16+r][g*32+kk*8 ..+8]

    const int tid = threadIdx.x;
    for (int e = tid; e < 1024; e += 256) {
        const int r_ = e & 15, g_ = (e >> 4) & 3, kkf = (e >> 6) & 3, ntf = e >> 8;
        const float* wr = w_h1 + (size_t)(ntf * 16 + r_) * 128 + g_ * 32 + kkf * 8;
        float4 f0 = *reinterpret_cast<const float4*>(wr);
        float4 f1 = *reinterpret_cast<const float4*>(wr + 4);
        bwlds[e] = pack8(f0, f1);
    }
    __syncthreads();

    const int lane = tid & 63;
    const int r = lane & 15, g = lane >> 4;

    const float s0 = sw[0], s1 = sw[1], s2 = sw[2];
    const float mx = fmaxf(s0, fmaxf(s1, s2));
    const float e0 = __expf(s0 - mx), e1 = __expf(s1 - mx), e2 = __expf(s2 - mx);
    const float inv = 1.0f / (e0 + e1 + e2);
    const float W0 = e0 * inv, W1 = e1 * inv, W2 = e2 * inv;
    const float cbias = W0 * b_h2[0] + W1 * b_c2[0] + W2 * b_b[0];

    float bh1v[4], wh2v[4];
#pragma unroll
    for (int nt = 0; nt < 4; ++nt) {
        bh1v[nt] = b_h1[nt * 16 + r];
        wh2v[nt] = w_h2[nt * 16 + r] * W0;   // W0 folded
    }
    f16x8 wc2r[4];                            // remapped: wc2r[kk][j] = w_c2[g*32+kk*8+j]
#pragma unroll
    for (int kk = 0; kk < 4; ++kk) {
        const int k0 = g * 32 + kk * 8;
        float4 f0 = *reinterpret_cast<const float4*>(w_c2 + k0);
        float4 f1 = *reinterpret_cast<const float4*>(w_c2 + k0 + 4);
        f0.x *= W1; f0.y *= W1; f0.z *= W1; f0.w *= W1;
        f1.x *= W1; f1.y *= W1; f1.z *= W1; f1.w *= W1;
        wc2r[kk] = pack8(f0, f1);   // W1 folded
    }
    const f16x8* myb = bwlds + g * 16 + r;

    const int gwid = (blockIdx.x * blockDim.x + tid) >> 6;
    const int nW = (gridDim.x * blockDim.x) >> 6;
    const int rsel = r & 3;
    const int srcl = ((r >> 2) << 4) | r;

    int b = gwid;
    int2 sd = make_int2(0, 0);
    if (b < NB) sd = edge2[b * 16 + r];

    for (; b < NB; b += nW) {
        const int bn = b + nW;
        int2 sdn = sd;
        if (bn < NB) sdn = edge2[bn * 16 + r];   // prefetch next iter's indices

        const int base = b * 16;
        const unsigned char* ps = Ps8 + (size_t)sd.x * SRCB;
        const unsigned char* pd = Pd8 + (size_t)sd.y * DSTB;

        // ---- issue all 16 gathers up front (all 16B, contiguous per region) ----
        uint4 a16[2], b16[2];
        f16x8 zs[4], yv[4], zd[4];
        a16[0] = *reinterpret_cast<const uint4*>(ps + g * 32);          // A' k g*32..+16
        a16[1] = *reinterpret_cast<const uint4*>(ps + g * 32 + 16);     // A' k +16..+32
        b16[0] = *reinterpret_cast<const uint4*>(pd + g * 32);          // B
        b16[1] = *reinterpret_cast<const uint4*>(pd + g * 32 + 16);
#pragma unroll
        for (int kk = 0; kk < 4; ++kk) {
            const int of = g * 64 + kk * 16;
            zs[kk] = *reinterpret_cast<const f16x8*>(ps + 128 + of);    // Zh[src]
            yv[kk] = *reinterpret_cast<const f16x8*>(pd + 128 + of);    // Y[dst]
            zd[kk] = *reinterpret_cast<const f16x8*>(pd + 384 + of);    // Zh[dst]
        }

        // ---- score1: H(16x64) = (zs .* zd) @ Wh1^T via MFMA (remapped k) ----
        f32x4 acc[4] = {};
#pragma unroll
        for (int kk = 0; kk < 4; ++kk) {
            f16x8 a = zs[kk] * zd[kk];
            mfma16(acc[0], a, myb[(0 * 4 + kk) * 64]);
            mfma16(acc[1], a, myb[(1 * 4 + kk) * 64]);
            mfma16(acc[2], a, myb[(2 * 4 + kk) * 64]);
            mfma16(acc[3], a, myb[(3 * 4 + kk) * 64]);
        }
        float t4[4];
#pragma unroll
        for (int rr = 0; rr < 4; ++rr) {
            float s = 0.f;
#pragma unroll
            for (int nt = 0; nt < 4; ++nt)
                s = fmaf(fmaxf(acc[nt][rr] + bh1v[nt], 0.f), wh2v[nt], s);
            t4[rr] = s;
        }
#pragma unroll
        for (int mask = 1; mask <= 8; mask <<= 1) {
#pragma unroll
            for (int rr = 0; rr < 4; ++rr)
                t4[rr] += __shfl_xor(t4[rr], mask, 16);
        }
        float u = t4[0];
        if (rsel == 1) u = t4[1];
        if (rsel == 2) u = t4[2];
        if (rsel == 3) u = t4[3];
        const float sc1w = __shfl(u, srcl, 64);  // W0-folded score1 of edge base+lane%16

        // ---- score2 (fp8 A'+B) & score3, same remapped k per kk ----
        float sA = 0.f, sB = 0.f;
#pragma unroll
        for (int h = 0; h < 2; ++h) {           // h covers kk = 2h (x,y) and 2h+1 (z,w)
            const unsigned ax = a16[h].x, ay = a16[h].y, az = a16[h].z, aw = a16[h].w;
            const unsigned bx = b16[h].x, by = b16[h].y, bz = b16[h].z, bw_ = b16[h].w;
            f32x2 pa0 = __builtin_amdgcn_cvt_pk_f32_fp8((int)ax, false);
            f32x2 pa1 = __builtin_amdgcn_cvt_pk_f32_fp8((int)ax, true);
            f32x2 pa2 = __builtin_amdgcn_cvt_pk_f32_fp8((int)ay, false);
            f32x2 pa3 = __builtin_amdgcn_cvt_pk_f32_fp8((int)ay, true);
            f32x2 pa4 = __builtin_amdgcn_cvt_pk_f32_fp8((int)az, false);
            f32x2 pa5 = __builtin_amdgcn_cvt_pk_f32_fp8((int)az, true);
            f32x2 pa6 = __builtin_amdgcn_cvt_pk_f32_fp8((int)aw, false);
            f32x2 pa7 = __builtin_amdgcn_cvt_pk_f32_fp8((int)aw, true);
            f32x2 pb0 = __builtin_amdgcn_cvt_pk_f32_fp8((int)bx, false);
            f32x2 pb1 = __builtin_amdgcn_cvt_pk_f32_fp8((int)bx, true);
            f32x2 pb2 = __builtin_amdgcn_cvt_pk_f32_fp8((int)by, false);
            f32x2 pb3 = __builtin_amdgcn_cvt_pk_f32_fp8((int)by, true);
            f32x2 pb4 = __builtin_amdgcn_cvt_pk_f32_fp8((int)bz, false);
            f32x2 pb5 = __builtin_amdgcn_cvt_pk_f32_fp8((int)bz, true);
            f32x2 pb6 = __builtin_amdgcn_cvt_pk_f32_fp8((int)bw_, false);
            f32x2 pb7 = __builtin_amdgcn_cvt_pk_f32_fp8((int)bw_, true);
            const f16x8 w0 = wc2r[2 * h], w1 = wc2r[2 * h + 1];
            sA = fmaf(fmaxf(pa0.x + pb0.x, 0.f), (float)w0[0], sA);
            sA = fmaf(fmaxf(pa0.y + pb0.y, 0.f), (float)w0[1], sA);
            sA = fmaf(fmaxf(pa1.x + pb1.x, 0.f), (float)w0[2], sA);
            sA = fmaf(fmaxf(pa1.y + pb1.y, 0.f), (float)w0[3], sA);
            sA = fmaf(fmaxf(pa2.x + pb2.x, 0.f), (float)w0[4], sA);
            sA = fmaf(fmaxf(pa2.y + pb2.y, 0.f), (float)w0[5], sA);
            sA = fmaf(fmaxf(pa3.x + pb3.x, 0.f), (float)w0[6], sA);
            sA = fmaf(fmaxf(pa3.y + pb3.y, 0.f), (float)w0[7], sA);
            sA = fmaf(fmaxf(pa4.x + pb4.x, 0.f), (float)w1[0], sA);
            sA = fmaf(fmaxf(pa4.y + pb4.y, 0.f), (float)w1[1], sA);
            sA = fmaf(fmaxf(pa5.x + pb5.x, 0.f), (float)w1[2], sA);
            sA = fmaf(fmaxf(pa5.y + pb5.y, 0.f), (float)w1[3], sA);
            sA = fmaf(fmaxf(pa6.x + pb6.x, 0.f), (float)w1[4], sA);
            sA = fmaf(fmaxf(pa6.y + pb6.y, 0.f), (float)w1[5], sA);
            sA = fmaf(fmaxf(pa7.x + pb7.x, 0.f), (float)w1[6], sA);
            sA = fmaf(fmaxf(pa7.y + pb7.y, 0.f), (float)w1[7], sA);
        }
#pragma unroll
        for (int kk = 0; kk < 4; ++kk)
#pragma unroll
            for (int j2 = 0; j2 < 4; ++j2)
                sB = fdot2(zs[kk], yv[kk], j2, sB);

        sA += __shfl_xor(sA, 16, 64);
        sA += __shfl_xor(sA, 32, 64);
        sB += __shfl_xor(sB, 16, 64);
        sB += __shfl_xor(sB, 32, 64);

        const float res = sc1w + sA + fmaf(W2, sB, cbias);
        if (lane < 16) out[base + lane] = res;
        sd = sdn;
    }
}

// ---------------- fallback: fused wave-per-edge, no workspace ----------------
__global__ __launch_bounds__(256) void fused_fallback(
    const float* __restrict__ z, const int* __restrict__ edge,
    const float* __restrict__ w_h1, const float* __restrict__ b_h1,
    const float* __restrict__ w_h2, const float* __restrict__ b_h2,
    const float* __restrict__ w_c1, const float* __restrict__ b_c1,
    const float* __restrict__ w_c2, const float* __restrict__ b_c2,
    const float* __restrict__ w_b, const float* __restrict__ b_b,
    const float* __restrict__ sw, float* __restrict__ out)
{
    __shared__ float zbuf[4][256];
    const int lane = threadIdx.x & 63;
    const int w = threadIdx.x >> 6;
    const int gw = blockIdx.x * 4 + w;
    const int nw = gridDim.x * 4;

    const float s0 = sw[0], s1 = sw[1], s2 = sw[2];
    const float mx = fmaxf(s0, fmaxf(s1, s2));
    const float e0 = __expf(s0 - mx), e1 = __expf(s1 - mx), e2 = __expf(s2 - mx);
    const float inv = 1.0f / (e0 + e1 + e2);
    const float W0 = e0 * inv, W1 = e1 * inv, W2 = e2 * inv;
    const float cbias = W0 * b_h2[0] + W1 * b_c2[0] + W2 * b_b[0];

    for (int e = gw; e < N_EDGES; e += nw) {
        const int src = edge[2 * e], dst = edge[2 * e + 1];
        const float zs0 = z[(size_t)src * 128 + lane];
        const float zs1 = z[(size_t)src * 128 + 64 + lane];
        const float zd0 = z[(size_t)dst * 128 + lane];
        const float zd1 = z[(size_t)dst * 128 + 64 + lane];
        zbuf[w][lane] = zs0; zbuf[w][64 + lane] = zs1;
        zbuf[w][128 + lane] = zd0; zbuf[w][192 + lane] = zd1;
        asm volatile("s_waitcnt lgkmcnt(0)" ::: "memory");

        float h = 0.f;
        const float* whr = w_h1 + (size_t)lane * 128;
        for (int d = 0; d < 128; ++d)
            h = fmaf(zbuf[w][d] * zbuf[w][128 + d], whr[d], h);
        float sc1 = fmaxf(h + b_h1[lane], 0.f) * w_h2[lane];

        float c0 = 0.f, c1 = 0.f;
        const float* w0r = w_c1 + (size_t)lane * 256;
        const float* w1r = w_c1 + (size_t)(lane + 64) * 256;
        for (int d = 0; d < 256; ++d) {
            const float cat = zbuf[w][d];
            c0 = fmaf(cat, w0r[d], c0);
            c1 = fmaf(cat, w1r[d], c1);
        }
        float sc2 = fmaxf(c0 + b_c1[lane], 0.f) * w_c2[lane]
                  + fmaxf(c1 + b_c1[lane + 64], 0.f) * w_c2[lane + 64];

        float t0 = 0.f, t1 = 0.f;
        const float* wb0 = w_b + (size_t)lane * 128;
        const float* wb1 = w_b + (size_t)(lane + 64) * 128;
        for (int f = 0; f < 128; ++f) {
            const float zdf = zbuf[w][128 + f];
            t0 = fmaf(wb0[f], zdf, t0);
            t1 = fmaf(wb1[f], zdf, t1);
        }
        float sc3 = zs0 * t0 + zs1 * t1;

        float v = fmaf(W0, sc1, fmaf(W1, sc2, W2 * sc3));
#pragma unroll
        for (int m = 1; m < 64; m <<= 1) v += __shfl_xor(v, m, 64);
        if (lane == 0) out[e] = v + cbias;
    }
}

extern "C" void kernel_launch(void* const* d_in, const int* in_sizes, int n_in,
                              void* d_out, int out_size, void* d_ws, size_t ws_size,
                              hipStream_t stream)
{
    const float* z    = (const float*)d_in[0];
    const int*   edge = (const int*)d_in[1];
    const float* w_h1 = (const float*)d_in[2];
    const float* b_h1 = (const float*)d_in[3];
    const float* w_h2 = (const float*)d_in[4];
    const float* b_h2 = (const float*)d_in[5];
    const float* w_c1 = (const float*)d_in[6];
    const float* b_c1 = (const float*)d_in[7];
    const float* w_c2 = (const float*)d_in[8];
    const float* b_c2 = (const float*)d_in[9];
    const float* w_b  = (const float*)d_in[10];
    const float* b_b  = (const float*)d_in[11];
    const float* sw   = (const float*)d_in[12];
    float* outp = (float*)d_out;

    const size_t szSrc = (size_t)N_NODES * SRCB;   // 38,400,000
    const size_t szDst = (size_t)N_NODES * DSTB;   // 64,000,000
    const size_t need  = szSrc + szDst;            // 102.4 MB (known to fit)

    if (ws_size >= need) {
        unsigned char* Ps8 = (unsigned char*)d_ws;
        unsigned char* Pd8 = (unsigned char*)d_ws + szSrc;
        hipLaunchKernelGGL(precomp_kernel, dim3(768), dim3(256), 0, stream,
                           z, w_c1, b_c1, w_b, Ps8, Pd8);
        hipLaunchKernelGGL(zb_kernel, dim3((N_NODES * 16 + 255) / 256), dim3(256),
                           0, stream, z, Ps8, Pd8);
        // ~110 VGPR -> 4 blocks/CU co-resident; 256 CU * 4 = 1024 (no tail)
        hipLaunchKernelGGL(edge_kernel, dim3(1024), dim3(256), 0, stream,
                           (const int2*)edge, Ps8, Pd8, w_h1, b_h1, w_h2, b_h2,
                           w_c2, b_c2, b_b, sw, outp);
    } else {
        hipLaunchKernelGGL(fused_fallback, dim3(4096), dim3(256), 0, stream,
                           z, edge, w_h1, b_h1, w_h2, b_h2, w_c1, b_c1,
                           w_c2, b_c2, w_b, b_b, sw, outp);
    }
}

// Round 11
// 203.277 us; speedup vs baseline: 3.7751x; 1.1076x over previous
//
#include <hip/hip_runtime.h>
#include <hip/hip_bf16.h>

#define N_NODES 100000
#define N_EDGES 1000000
// SoA node tables in d_ws:
//   P_src[node] (384B): [A' fp8e4m3 x128 | Zh16 f16 x128]   (A' = Wc1a@z + b_c1)
//   P_dst[node] (512B): [B  fp8e4m3 x128 | Y f16 x128 | Zh8 fp8 x128]
//     B = Wc1b@z (bias folded into A'), Y = Wb@z
// Edge-kernel k-map (lane g, mfma kk, elem j): k = g*32 + kk*8 + j
//   -> per-lane contiguous runs: A'/B/Zh8 32B, Zh16/Y 64B (all 16B loads)
#define SRCB 384
#define DSTB 512
#define NB (N_EDGES / 16)       // 62500

typedef float f32x4 __attribute__((ext_vector_type(4)));
typedef float f32x2 __attribute__((ext_vector_type(2)));
typedef _Float16 f16x8 __attribute__((ext_vector_type(8)));
typedef _Float16 f16x2 __attribute__((ext_vector_type(2)));

__device__ inline f16x8 pack8(float4 a, float4 b) {
    f16x8 o;
    o[0] = (_Float16)a.x; o[1] = (_Float16)a.y; o[2] = (_Float16)a.z; o[3] = (_Float16)a.w;
    o[4] = (_Float16)b.x; o[5] = (_Float16)b.y; o[6] = (_Float16)b.z; o[7] = (_Float16)b.w;
    return o;
}
__device__ inline void mfma16(f32x4& acc, f16x8 a, f16x8 b) {
    acc = __builtin_amdgcn_mfma_f32_16x16x32_f16(a, b, acc, 0, 0, 0);
}
__device__ inline float fdot2(f16x8 a, f16x8 b, int j2, float c) {
    f16x2 pa = { a[2 * j2], a[2 * j2 + 1] };
    f16x2 pb = { b[2 * j2], b[2 * j2 + 1] };
    return __builtin_amdgcn_fdot2(pa, pb, c, false);
}
__device__ inline unsigned char f2fp8(float v) {
    int p = __builtin_amdgcn_cvt_pk_fp8_f32(v, v, 0, false);
    return (unsigned char)(p & 0xff);
}

// ---- precompute (round-2 measured structure): GEMM cols 0..383 over 6 col-tiles ----
// ct 0-1 -> A' (fp8, P_src, +b_c1) ; ct 2-3 -> B (fp8, P_dst) ; ct 4-5 -> Y (f16, P_dst)
__global__ __launch_bounds__(256) void precomp_kernel(
    const float* __restrict__ z, const float* __restrict__ w_c1,
    const float* __restrict__ b_c1, const float* __restrict__ w_b,
    unsigned char* __restrict__ Ps8, unsigned char* __restrict__ Pd8)
{
    const int lane = threadIdx.x & 63;
    const int r = lane & 15, g = lane >> 4;
    const int wid = blockIdx.x * 4 + (threadIdx.x >> 6);
    const int ct = wid % 6;          // 6 col-tiles of 64 over 384 output cols
    const int walker = wid / 6;
    const int nWalk = (gridDim.x * 4) / 6;
    if (walker >= nWalk) return;

    f16x8 bw[4][4];                  // B-fragments, loaded once
#pragma unroll
    for (int nt = 0; nt < 4; ++nt) {
        const int c = ct * 64 + nt * 16 + r;
        const float* wrow;
        if (c < 128)       wrow = w_c1 + (size_t)c * 256;               // Wc1a row
        else if (c < 256)  wrow = w_c1 + (size_t)(c - 128) * 256 + 128; // Wc1b row
        else               wrow = w_b + (size_t)(c - 256) * 128;        // Wb row
#pragma unroll
        for (int kk = 0; kk < 4; ++kk) {
            const int k0 = kk * 32 + g * 8;
            float4 f0 = *reinterpret_cast<const float4*>(wrow + k0);
            float4 f1 = *reinterpret_cast<const float4*>(wrow + k0 + 4);
            bw[nt][kk] = pack8(f0, f1);
        }
    }
    float bc1v[4] = {0.f, 0.f, 0.f, 0.f};
    if (ct < 2) {
#pragma unroll
        for (int nt = 0; nt < 4; ++nt) bc1v[nt] = b_c1[ct * 64 + nt * 16 + r];
    }

    for (int nb = walker; nb < N_NODES / 16; nb += nWalk) {
        const float* zp = z + (size_t)(nb * 16 + r) * 128;
        f32x4 acc[4] = {};
#pragma unroll
        for (int kk = 0; kk < 4; ++kk) {
            const int k0 = kk * 32 + g * 8;
            float4 z0 = *reinterpret_cast<const float4*>(zp + k0);
            float4 z1 = *reinterpret_cast<const float4*>(zp + k0 + 4);
            f16x8 a = pack8(z0, z1);
#pragma unroll
            for (int nt = 0; nt < 4; ++nt) mfma16(acc[nt], a, bw[nt][kk]);
        }
#pragma unroll
        for (int nt = 0; nt < 4; ++nt) {
#pragma unroll
            for (int rr = 0; rr < 4; ++rr) {
                const float v = acc[nt][rr] + bc1v[nt];
                const int node = nb * 16 + g * 4 + rr;
                const int c = ct * 64 + nt * 16 + r;
                if (ct < 2) {
                    Ps8[(size_t)node * SRCB + c] = f2fp8(v);                  // A'
                } else if (ct < 4) {
                    Pd8[(size_t)node * DSTB + (c - 128)] = f2fp8(v);          // B
                } else {
                    *reinterpret_cast<_Float16*>(
                        Pd8 + (size_t)node * DSTB + 128 + (size_t)(c - 256) * 2)
                        = (_Float16)v;                                        // Y
                }
            }
        }
    }
}

// ---- Zh: f16 z into P_src[128..383]; fp8 z into P_dst[384..511] ----
__global__ __launch_bounds__(256) void zb_kernel(const float* __restrict__ z,
                                                 unsigned char* __restrict__ Ps8,
                                                 unsigned char* __restrict__ Pd8)
{
    const int i = blockIdx.x * 256 + threadIdx.x;
    if (i >= N_NODES * 16) return;
    const int node = i >> 4, ch = i & 15;
    const float* zp = z + (size_t)node * 128 + ch * 8;
    float4 a = *reinterpret_cast<const float4*>(zp);
    float4 b = *reinterpret_cast<const float4*>(zp + 4);
    *reinterpret_cast<f16x8*>(Ps8 + (size_t)node * SRCB + 128 + ch * 16) = pack8(a, b);
    int w0 = __builtin_amdgcn_cvt_pk_fp8_f32(a.x, a.y, 0, false);
    w0 = __builtin_amdgcn_cvt_pk_fp8_f32(a.z, a.w, w0, true);
    int w1 = __builtin_amdgcn_cvt_pk_fp8_f32(b.x, b.y, 0, false);
    w1 = __builtin_amdgcn_cvt_pk_fp8_f32(b.z, b.w, w1, true);
    uint2 pk; pk.x = (unsigned)w0; pk.y = (unsigned)w1;
    *reinterpret_cast<uint2*>(Pd8 + (size_t)node * DSTB + 384 + ch * 8) = pk;
}

// ---- main edge kernel: 16 edges/wave; all-16B contiguous loads; fp8 A'/B/Zh_d ----
// lane = g*16 + r : edge = b*16 + r; k(kk,g,j) = g*32 + kk*8 + j
__global__ __launch_bounds__(256) void edge_kernel(
    const int2* __restrict__ edge2,
    const unsigned char* __restrict__ Ps8, const unsigned char* __restrict__ Pd8,
    const float* __restrict__ w_h1, const float* __restrict__ b_h1,
    const float* __restrict__ w_h2, const float* __restrict__ b_h2,
    const float* __restrict__ w_c2, const float* __restrict__ b_c2,
    const float* __restrict__ b_b, const float* __restrict__ sw,
    float* __restrict__ out)
{
    __shared__ f16x8 bwlds[1024];   // entry (nt,kk,g,r): w_h1[nt*16+r][g*32+kk*8 ..+8]

    const int tid = threadIdx.x;
    for (int e = tid; e < 1024; e += 256) {
        const int r_ = e & 15, g_ = (e >> 4) & 3, kkf = (e >> 6) & 3, ntf = e >> 8;
        const float* wr = w_h1 + (size_t)(ntf * 16 + r_) * 128 + g_ * 32 + kkf * 8;
        float4 f0 = *reinterpret_cast<const float4*>(wr);
        float4 f1 = *reinterpret_cast<const float4*>(wr + 4);
        bwlds[e] = pack8(f0, f1);
    }
    __syncthreads();

    const int lane = tid & 63;
    const int r = lane & 15, g = lane >> 4;

    const float s0 = sw[0], s1 = sw[1], s2 = sw[2];
    const float mx = fmaxf(s0, fmaxf(s1, s2));
    const float e0 = __expf(s0 - mx), e1 = __expf(s1 - mx), e2 = __expf(s2 - mx);
    const float inv = 1.0f / (e0 + e1 + e2);
    const float W0 = e0 * inv, W1 = e1 * inv, W2 = e2 * inv;
    const float cbias = W0 * b_h2[0] + W1 * b_c2[0] + W2 * b_b[0];

    float bh1v[4], wh2v[4];
#pragma unroll
    for (int nt = 0; nt < 4; ++nt) {
        bh1v[nt] = b_h1[nt * 16 + r];
        wh2v[nt] = w_h2[nt * 16 + r] * W0;   // W0 folded
    }
    f16x8 wc2r[4];                            // wc2r[kk][j] = W1 * w_c2[g*32+kk*8+j]
#pragma unroll
    for (int kk = 0; kk < 4; ++kk) {
        const int k0 = g * 32 + kk * 8;
        float4 f0 = *reinterpret_cast<const float4*>(w_c2 + k0);
        float4 f1 = *reinterpret_cast<const float4*>(w_c2 + k0 + 4);
        f0.x *= W1; f0.y *= W1; f0.z *= W1; f0.w *= W1;
        f1.x *= W1; f1.y *= W1; f1.z *= W1; f1.w *= W1;
        wc2r[kk] = pack8(f0, f1);
    }
    const f16x8* myb = bwlds + g * 16 + r;

    const int gwid = (blockIdx.x * blockDim.x + tid) >> 6;
    const int nW = (gridDim.x * blockDim.x) >> 6;
    const int rsel = r & 3;
    const int srcl = ((r >> 2) << 4) | r;

    int b = gwid;
    int2 sd = make_int2(0, 0);
    if (b < NB) sd = edge2[b * 16 + r];

    for (; b < NB; b += nW) {
        const int bn = b + nW;
        int2 sdn = sd;
        if (bn < NB) sdn = edge2[bn * 16 + r];   // prefetch next iter's indices

        const int base = b * 16;
        const unsigned char* ps = Ps8 + (size_t)sd.x * SRCB;
        const unsigned char* pd = Pd8 + (size_t)sd.y * DSTB;

        // ---- issue all 14 gathers up front (all 16B, contiguous per region) ----
        uint4 a16[2], b16[2], zq[2];
        f16x8 zs[4], yv[4];
        a16[0] = *reinterpret_cast<const uint4*>(ps + g * 32);          // A' fp8
        a16[1] = *reinterpret_cast<const uint4*>(ps + g * 32 + 16);
        b16[0] = *reinterpret_cast<const uint4*>(pd + g * 32);          // B fp8
        b16[1] = *reinterpret_cast<const uint4*>(pd + g * 32 + 16);
        zq[0]  = *reinterpret_cast<const uint4*>(pd + 384 + g * 32);    // Zh8[dst]
        zq[1]  = *reinterpret_cast<const uint4*>(pd + 384 + g * 32 + 16);
#pragma unroll
        for (int kk = 0; kk < 4; ++kk) {
            const int of = g * 64 + kk * 16;
            zs[kk] = *reinterpret_cast<const f16x8*>(ps + 128 + of);    // Zh16[src]
            yv[kk] = *reinterpret_cast<const f16x8*>(pd + 128 + of);    // Y[dst]
        }
        const unsigned zdw[8] = { zq[0].x, zq[0].y, zq[0].z, zq[0].w,
                                  zq[1].x, zq[1].y, zq[1].z, zq[1].w };

        // ---- score1: H(16x64) = (zs .* fp8(zd)) @ Wh1^T via MFMA ----
        f32x4 acc[4] = {};
#pragma unroll
        for (int kk = 0; kk < 4; ++kk) {
            f32x2 p0 = __builtin_amdgcn_cvt_pk_f32_fp8((int)zdw[2 * kk], false);
            f32x2 p1 = __builtin_amdgcn_cvt_pk_f32_fp8((int)zdw[2 * kk], true);
            f32x2 p2 = __builtin_amdgcn_cvt_pk_f32_fp8((int)zdw[2 * kk + 1], false);
            f32x2 p3 = __builtin_amdgcn_cvt_pk_f32_fp8((int)zdw[2 * kk + 1], true);
            f16x8 a;
            a[0] = (_Float16)((float)zs[kk][0] * p0.x);
            a[1] = (_Float16)((float)zs[kk][1] * p0.y);
            a[2] = (_Float16)((float)zs[kk][2] * p1.x);
            a[3] = (_Float16)((float)zs[kk][3] * p1.y);
            a[4] = (_Float16)((float)zs[kk][4] * p2.x);
            a[5] = (_Float16)((float)zs[kk][5] * p2.y);
            a[6] = (_Float16)((float)zs[kk][6] * p3.x);
            a[7] = (_Float16)((float)zs[kk][7] * p3.y);
            mfma16(acc[0], a, myb[(0 * 4 + kk) * 64]);
            mfma16(acc[1], a, myb[(1 * 4 + kk) * 64]);
            mfma16(acc[2], a, myb[(2 * 4 + kk) * 64]);
            mfma16(acc[3], a, myb[(3 * 4 + kk) * 64]);
        }
        float t4[4];
#pragma unroll
        for (int rr = 0; rr < 4; ++rr) {
            float s = 0.f;
#pragma unroll
            for (int nt = 0; nt < 4; ++nt)
                s = fmaf(fmaxf(acc[nt][rr] + bh1v[nt], 0.f), wh2v[nt], s);
            t4[rr] = s;
        }
#pragma unroll
        for (int mask = 1; mask <= 8; mask <<= 1) {
#pragma unroll
            for (int rr = 0; rr < 4; ++rr)
                t4[rr] += __shfl_xor(t4[rr], mask, 16);
        }
        float u = t4[0];
        if (rsel == 1) u = t4[1];
        if (rsel == 2) u = t4[2];
        if (rsel == 3) u = t4[3];
        const float sc1w = __shfl(u, srcl, 64);  // W0-folded score1 of edge base+lane%16

        // ---- score2 (fp8 A'+B) & score3 (f16 zs . Y) ----
        float sA = 0.f, sB = 0.f;
#pragma unroll
        for (int h = 0; h < 2; ++h) {
            const unsigned ax = a16[h].x, ay = a16[h].y, az = a16[h].z, aw = a16[h].w;
            const unsigned bx = b16[h].x, by = b16[h].y, bz = b16[h].z, bw_ = b16[h].w;
            f32x2 pa0 = __builtin_amdgcn_cvt_pk_f32_fp8((int)ax, false);
            f32x2 pa1 = __builtin_amdgcn_cvt_pk_f32_fp8((int)ax, true);
            f32x2 pa2 = __builtin_amdgcn_cvt_pk_f32_fp8((int)ay, false);
            f32x2 pa3 = __builtin_amdgcn_cvt_pk_f32_fp8((int)ay, true);
            f32x2 pa4 = __builtin_amdgcn_cvt_pk_f32_fp8((int)az, false);
            f32x2 pa5 = __builtin_amdgcn_cvt_pk_f32_fp8((int)az, true);
            f32x2 pa6 = __builtin_amdgcn_cvt_pk_f32_fp8((int)aw, false);
            f32x2 pa7 = __builtin_amdgcn_cvt_pk_f32_fp8((int)aw, true);
            f32x2 pb0 = __builtin_amdgcn_cvt_pk_f32_fp8((int)bx, false);
            f32x2 pb1 = __builtin_amdgcn_cvt_pk_f32_fp8((int)bx, true);
            f32x2 pb2 = __builtin_amdgcn_cvt_pk_f32_fp8((int)by, false);
            f32x2 pb3 = __builtin_amdgcn_cvt_pk_f32_fp8((int)by, true);
            f32x2 pb4 = __builtin_amdgcn_cvt_pk_f32_fp8((int)bz, false);
            f32x2 pb5 = __builtin_amdgcn_cvt_pk_f32_fp8((int)bz, true);
            f32x2 pb6 = __builtin_amdgcn_cvt_pk_f32_fp8((int)bw_, false);
            f32x2 pb7 = __builtin_amdgcn_cvt_pk_f32_fp8((int)bw_, true);
            const f16x8 w0 = wc2r[2 * h], w1 = wc2r[2 * h + 1];
            sA = fmaf(fmaxf(pa0.x + pb0.x, 0.f), (float)w0[0], sA);
            sA = fmaf(fmaxf(pa0.y + pb0.y, 0.f), (float)w0[1], sA);
            sA = fmaf(fmaxf(pa1.x + pb1.x, 0.f), (float)w0[2], sA);
            sA = fmaf(fmaxf(pa1.y + pb1.y, 0.f), (float)w0[3], sA);
            sA = fmaf(fmaxf(pa2.x + pb2.x, 0.f), (float)w0[4], sA);
            sA = fmaf(fmaxf(pa2.y + pb2.y, 0.f), (float)w0[5], sA);
            sA = fmaf(fmaxf(pa3.x + pb3.x, 0.f), (float)w0[6], sA);
            sA = fmaf(fmaxf(pa3.y + pb3.y, 0.f), (float)w0[7], sA);
            sA = fmaf(fmaxf(pa4.x + pb4.x, 0.f), (float)w1[0], sA);
            sA = fmaf(fmaxf(pa4.y + pb4.y, 0.f), (float)w1[1], sA);
            sA = fmaf(fmaxf(pa5.x + pb5.x, 0.f), (float)w1[2], sA);
            sA = fmaf(fmaxf(pa5.y + pb5.y, 0.f), (float)w1[3], sA);
            sA = fmaf(fmaxf(pa6.x + pb6.x, 0.f), (float)w1[4], sA);
            sA = fmaf(fmaxf(pa6.y + pb6.y, 0.f), (float)w1[5], sA);
            sA = fmaf(fmaxf(pa7.x + pb7.x, 0.f), (float)w1[6], sA);
            sA = fmaf(fmaxf(pa7.y + pb7.y, 0.f), (float)w1[7], sA);
        }
#pragma unroll
        for (int kk = 0; kk < 4; ++kk)
#pragma unroll
            for (int j2 = 0; j2 < 4; ++j2)
                sB = fdot2(zs[kk], yv[kk], j2, sB);

        sA += __shfl_xor(sA, 16, 64);
        sA += __shfl_xor(sA, 32, 64);
        sB += __shfl_xor(sB, 16, 64);
        sB += __shfl_xor(sB, 32, 64);

        const float res = sc1w + sA + fmaf(W2, sB, cbias);
        if (lane < 16) out[base + lane] = res;
        sd = sdn;
    }
}

// ---------------- fallback: fused wave-per-edge, no workspace ----------------
__global__ __launch_bounds__(256) void fused_fallback(
    const float* __restrict__ z, const int* __restrict__ edge,
    const float* __restrict__ w_h1, const float* __restrict__ b_h1,
    const float* __restrict__ w_h2, const float* __restrict__ b_h2,
    const float* __restrict__ w_c1, const float* __restrict__ b_c1,
    const float* __restrict__ w_c2, const float* __restrict__ b_c2,
    const float* __restrict__ w_b, const float* __restrict__ b_b,
    const float* __restrict__ sw, float* __restrict__ out)
{
    __shared__ float zbuf[4][256];
    const int lane = threadIdx.x & 63;
    const int w = threadIdx.x >> 6;
    const int gw = blockIdx.x * 4 + w;
    const int nw = gridDim.x * 4;

    const float s0 = sw[0], s1 = sw[1], s2 = sw[2];
    const float mx = fmaxf(s0, fmaxf(s1, s2));
    const float e0 = __expf(s0 - mx), e1 = __expf(s1 - mx), e2 = __expf(s2 - mx);
    const float inv = 1.0f / (e0 + e1 + e2);
    const float W0 = e0 * inv, W1 = e1 * inv, W2 = e2 * inv;
    const float cbias = W0 * b_h2[0] + W1 * b_c2[0] + W2 * b_b[0];

    for (int e = gw; e < N_EDGES; e += nw) {
        const int src = edge[2 * e], dst = edge[2 * e + 1];
        const float zs0 = z[(size_t)src * 128 + lane];
        const float zs1 = z[(size_t)src * 128 + 64 + lane];
        const float zd0 = z[(size_t)dst * 128 + lane];
        const float zd1 = z[(size_t)dst * 128 + 64 + lane];
        zbuf[w][lane] = zs0; zbuf[w][64 + lane] = zs1;
        zbuf[w][128 + lane] = zd0; zbuf[w][192 + lane] = zd1;
        asm volatile("s_waitcnt lgkmcnt(0)" ::: "memory");

        float h = 0.f;
        const float* whr = w_h1 + (size_t)lane * 128;
        for (int d = 0; d < 128; ++d)
            h = fmaf(zbuf[w][d] * zbuf[w][128 + d], whr[d], h);
        float sc1 = fmaxf(h + b_h1[lane], 0.f) * w_h2[lane];

        float c0 = 0.f, c1 = 0.f;
        const float* w0r = w_c1 + (size_t)lane * 256;
        const float* w1r = w_c1 + (size_t)(lane + 64) * 256;
        for (int d = 0; d < 256; ++d) {
            const float cat = zbuf[w][d];
            c0 = fmaf(cat, w0r[d], c0);
            c1 = fmaf(cat, w1r[d], c1);
        }
        float sc2 = fmaxf(c0 + b_c1[lane], 0.f) * w_c2[lane]
                  + fmaxf(c1 + b_c1[lane + 64], 0.f) * w_c2[lane + 64];

        float t0 = 0.f, t1 = 0.f;
        const float* wb0 = w_b + (size_t)lane * 128;
        const float* wb1 = w_b + (size_t)(lane + 64) * 128;
        for (int f = 0; f < 128; ++f) {
            const float zdf = zbuf[w][128 + f];
            t0 = fmaf(wb0[f], zdf, t0);
            t1 = fmaf(wb1[f], zdf, t1);
        }
        float sc3 = zs0 * t0 + zs1 * t1;

        float v = fmaf(W0, sc1, fmaf(W1, sc2, W2 * sc3));
#pragma unroll
        for (int m = 1; m < 64; m <<= 1) v += __shfl_xor(v, m, 64);
        if (lane == 0) out[e] = v + cbias;
    }
}

extern "C" void kernel_launch(void* const* d_in, const int* in_sizes, int n_in,
                              void* d_out, int out_size, void* d_ws, size_t ws_size,
                              hipStream_t stream)
{
    const float* z    = (const float*)d_in[0];
    const int*   edge = (const int*)d_in[1];
    const float* w_h1 = (const float*)d_in[2];
    const float* b_h1 = (const float*)d_in[3];
    const float* w_h2 = (const float*)d_in[4];
    const float* b_h2 = (const float*)d_in[5];
    const float* w_c1 = (const float*)d_in[6];
    const float* b_c1 = (const float*)d_in[7];
    const float* w_c2 = (const float*)d_in[8];
    const float* b_c2 = (const float*)d_in[9];
    const float* w_b  = (const float*)d_in[10];
    const float* b_b  = (const float*)d_in[11];
    const float* sw   = (const float*)d_in[12];
    float* outp = (float*)d_out;

    const size_t szSrc = (size_t)N_NODES * SRCB;   // 38,400,000
    const size_t szDst = (size_t)N_NODES * DSTB;   // 51,200,000
    const size_t need  = szSrc + szDst;            // 89.6 MB

    if (ws_size >= need) {
        unsigned char* Ps8 = (unsigned char*)d_ws;
        unsigned char* Pd8 = (unsigned char*)d_ws + szSrc;
        hipLaunchKernelGGL(precomp_kernel, dim3(768), dim3(256), 0, stream,
                           z, w_c1, b_c1, w_b, Ps8, Pd8);
        hipLaunchKernelGGL(zb_kernel, dim3((N_NODES * 16 + 255) / 256), dim3(256),
                           0, stream, z, Ps8, Pd8);
        hipLaunchKernelGGL(edge_kernel, dim3(1024), dim3(256), 0, stream,
                           (const int2*)edge, Ps8, Pd8, w_h1, b_h1, w_h2, b_h2,
                           w_c2, b_c2, b_b, sw, outp);
    } else {
        hipLaunchKernelGGL(fused_fallback, dim3(4096), dim3(256), 0, stream,
                           z, edge, w_h1, b_h1, w_h2, b_h2, w_c1, b_c1,
                           w_c2, b_c2, w_b, b_b, sw, outp);
    }
}

// Round 12
// 188.662 us; speedup vs baseline: 4.0675x; 1.0775x over previous
//
#include <hip/hip_runtime.h>
#include <hip/hip_bf16.h>

#define N_NODES 100000
#define N_EDGES 1000000
// SoA node tables in d_ws:
//   P_src[node] (384B): [A' fp8e4m3 x128 | Zh16 f16 x128]   (A' = Wc1a@z + b_c1)
//   P_dst[node] (512B): [B  fp8e4m3 x128 | Y f16 x128 | Zh8 fp8 x128]
//     B = Wc1b@z (bias folded into A'), Y = Wb@z
// Edge-kernel k-map (lane g, mfma kk, elem j): k = g*32 + kk*8 + j
#define SRCB 384
#define DSTB 512
#define NB (N_EDGES / 16)       // 62500
#define NCHUNK (N_NODES / 16)   // 6250

typedef float f32x4 __attribute__((ext_vector_type(4)));
typedef float f32x2 __attribute__((ext_vector_type(2)));
typedef _Float16 f16x8 __attribute__((ext_vector_type(8)));
typedef _Float16 f16x2 __attribute__((ext_vector_type(2)));

__device__ inline f16x8 pack8(float4 a, float4 b) {
    f16x8 o;
    o[0] = (_Float16)a.x; o[1] = (_Float16)a.y; o[2] = (_Float16)a.z; o[3] = (_Float16)a.w;
    o[4] = (_Float16)b.x; o[5] = (_Float16)b.y; o[6] = (_Float16)b.z; o[7] = (_Float16)b.w;
    return o;
}
__device__ inline void mfma16(f32x4& acc, f16x8 a, f16x8 b) {
    acc = __builtin_amdgcn_mfma_f32_16x16x32_f16(a, b, acc, 0, 0, 0);
}
__device__ inline float fdot2(f16x8 a, f16x8 b, int j2, float c) {
    f16x2 pa = { a[2 * j2], a[2 * j2 + 1] };
    f16x2 pb = { b[2 * j2], b[2 * j2 + 1] };
    return __builtin_amdgcn_fdot2(pa, pb, c, false);
}
__device__ inline unsigned char f2fp8(float v) {
    int p = __builtin_amdgcn_cvt_pk_fp8_f32(v, v, 0, false);
    return (unsigned char)(p & 0xff);
}

// ---- precompute v4: weights in LDS, 2 phases x 3 col-tiles, no per-chunk barriers.
// Each wave streams node chunks independently; Zh16/Zh8 fused into phase 0.
__global__ __launch_bounds__(512) void precomp_kernel(
    const float* __restrict__ z, const float* __restrict__ w_c1,
    const float* __restrict__ b_c1, const float* __restrict__ w_b,
    unsigned char* __restrict__ Ps8, unsigned char* __restrict__ Pd8)
{
    __shared__ f16x8 wlds[3072];   // 48 KB: 3 ct x 4 nt x 4 kk x 64 lanes

    const int tid = threadIdx.x;
    const int w = tid >> 6;
    const int lane = tid & 63;
    const int r = lane & 15, g = lane >> 4;
    const int gw = blockIdx.x * 8 + w;
    const int nW = gridDim.x * 8;

    float bc1v[2][4];
#pragma unroll
    for (int t = 0; t < 2; ++t)
#pragma unroll
        for (int nt = 0; nt < 4; ++nt)
            bc1v[t][nt] = b_c1[t * 64 + nt * 16 + r];

    for (int phase = 0; phase < 2; ++phase) {
        if (phase) __syncthreads();   // drain phase-0 ds_reads before restage
        // stage B-fragments for ct = phase*3 .. +2  (idx: ((t*4+nt)*4+kk)*64+g*16+r)
        for (int i = tid; i < 3072; i += 512) {
            const int r_ = i & 15, g_ = (i >> 4) & 3, kk = (i >> 6) & 3;
            const int nt = (i >> 8) & 3, t = i >> 10;
            const int c = (phase * 3 + t) * 64 + nt * 16 + r_;
            const float* wrow;
            if (c < 128)       wrow = w_c1 + (size_t)c * 256;               // Wc1a
            else if (c < 256)  wrow = w_c1 + (size_t)(c - 128) * 256 + 128; // Wc1b
            else               wrow = w_b + (size_t)(c - 256) * 128;        // Wb
            const int k0 = kk * 32 + g_ * 8;
            float4 f0 = *reinterpret_cast<const float4*>(wrow + k0);
            float4 f1 = *reinterpret_cast<const float4*>(wrow + k0 + 4);
            wlds[i] = pack8(f0, f1);
        }
        __syncthreads();

        const f16x8* myw = wlds + g * 16 + r;

        for (int nb = gw; nb < NCHUNK; nb += nW) {
            const int node_r = nb * 16 + r;
            const float* zp = z + (size_t)node_r * 128;
            f16x8 a[4];
#pragma unroll
            for (int kk = 0; kk < 4; ++kk) {
                const int k0 = kk * 32 + g * 8;
                float4 z0 = *reinterpret_cast<const float4*>(zp + k0);
                float4 z1 = *reinterpret_cast<const float4*>(zp + k0 + 4);
                a[kk] = pack8(z0, z1);
                if (phase == 0) {
                    // fused Zh16 (src) + Zh8 (dst) writes
                    *reinterpret_cast<f16x8*>(
                        Ps8 + (size_t)node_r * SRCB + 128 + k0 * 2) = a[kk];
                    int q0 = __builtin_amdgcn_cvt_pk_fp8_f32(z0.x, z0.y, 0, false);
                    q0 = __builtin_amdgcn_cvt_pk_fp8_f32(z0.z, z0.w, q0, true);
                    int q1 = __builtin_amdgcn_cvt_pk_fp8_f32(z1.x, z1.y, 0, false);
                    q1 = __builtin_amdgcn_cvt_pk_fp8_f32(z1.z, z1.w, q1, true);
                    uint2 pk; pk.x = (unsigned)q0; pk.y = (unsigned)q1;
                    *reinterpret_cast<uint2*>(
                        Pd8 + (size_t)node_r * DSTB + 384 + k0) = pk;
                }
            }
#pragma unroll
            for (int t = 0; t < 3; ++t) {
                const int ct = phase * 3 + t;
                f32x4 acc[4] = {};
#pragma unroll
                for (int kk = 0; kk < 4; ++kk) {
#pragma unroll
                    for (int nt = 0; nt < 4; ++nt)
                        mfma16(acc[nt], a[kk], myw[((t * 4 + nt) * 4 + kk) * 64]);
                }
#pragma unroll
                for (int nt = 0; nt < 4; ++nt) {
#pragma unroll
                    for (int rr = 0; rr < 4; ++rr) {
                        const int node = nb * 16 + g * 4 + rr;
                        const int c = ct * 64 + nt * 16 + r;
                        float v = acc[nt][rr];
                        if (ct < 2) {
                            v += bc1v[ct][nt];
                            Ps8[(size_t)node * SRCB + c] = f2fp8(v);            // A'
                        } else if (ct < 4) {
                            Pd8[(size_t)node * DSTB + (c - 128)] = f2fp8(v);    // B
                        } else {
                            *reinterpret_cast<_Float16*>(
                                Pd8 + (size_t)node * DSTB + 128
                                    + (size_t)(c - 256) * 2) = (_Float16)v;     // Y
                        }
                    }
                }
            }
        }
    }
}

// ---- main edge kernel (unchanged from round 11; measured 140us / 422MB) ----
// lane = g*16 + r : edge = b*16 + r; k(kk,g,j) = g*32 + kk*8 + j
__global__ __launch_bounds__(256) void edge_kernel(
    const int2* __restrict__ edge2,
    const unsigned char* __restrict__ Ps8, const unsigned char* __restrict__ Pd8,
    const float* __restrict__ w_h1, const float* __restrict__ b_h1,
    const float* __restrict__ w_h2, const float* __restrict__ b_h2,
    const float* __restrict__ w_c2, const float* __restrict__ b_c2,
    const float* __restrict__ b_b, const float* __restrict__ sw,
    float* __restrict__ out)
{
    __shared__ f16x8 bwlds[1024];   // entry (nt,kk,g,r): w_h1[nt*16+r][g*32+kk*8 ..+8]

    const int tid = threadIdx.x;
    for (int e = tid; e < 1024; e += 256) {
        const int r_ = e & 15, g_ = (e >> 4) & 3, kkf = (e >> 6) & 3, ntf = e >> 8;
        const float* wr = w_h1 + (size_t)(ntf * 16 + r_) * 128 + g_ * 32 + kkf * 8;
        float4 f0 = *reinterpret_cast<const float4*>(wr);
        float4 f1 = *reinterpret_cast<const float4*>(wr + 4);
        bwlds[e] = pack8(f0, f1);
    }
    __syncthreads();

    const int lane = tid & 63;
    const int r = lane & 15, g = lane >> 4;

    const float s0 = sw[0], s1 = sw[1], s2 = sw[2];
    const float mx = fmaxf(s0, fmaxf(s1, s2));
    const float e0 = __expf(s0 - mx), e1 = __expf(s1 - mx), e2 = __expf(s2 - mx);
    const float inv = 1.0f / (e0 + e1 + e2);
    const float W0 = e0 * inv, W1 = e1 * inv, W2 = e2 * inv;
    const float cbias = W0 * b_h2[0] + W1 * b_c2[0] + W2 * b_b[0];

    float bh1v[4], wh2v[4];
#pragma unroll
    for (int nt = 0; nt < 4; ++nt) {
        bh1v[nt] = b_h1[nt * 16 + r];
        wh2v[nt] = w_h2[nt * 16 + r] * W0;   // W0 folded
    }
    f16x8 wc2r[4];                            // wc2r[kk][j] = W1 * w_c2[g*32+kk*8+j]
#pragma unroll
    for (int kk = 0; kk < 4; ++kk) {
        const int k0 = g * 32 + kk * 8;
        float4 f0 = *reinterpret_cast<const float4*>(w_c2 + k0);
        float4 f1 = *reinterpret_cast<const float4*>(w_c2 + k0 + 4);
        f0.x *= W1; f0.y *= W1; f0.z *= W1; f0.w *= W1;
        f1.x *= W1; f1.y *= W1; f1.z *= W1; f1.w *= W1;
        wc2r[kk] = pack8(f0, f1);
    }
    const f16x8* myb = bwlds + g * 16 + r;

    const int gwid = (blockIdx.x * blockDim.x + tid) >> 6;
    const int nW = (gridDim.x * blockDim.x) >> 6;
    const int rsel = r & 3;
    const int srcl = ((r >> 2) << 4) | r;

    int b = gwid;
    int2 sd = make_int2(0, 0);
    if (b < NB) sd = edge2[b * 16 + r];

    for (; b < NB; b += nW) {
        const int bn = b + nW;
        int2 sdn = sd;
        if (bn < NB) sdn = edge2[bn * 16 + r];   // prefetch next iter's indices

        const int base = b * 16;
        const unsigned char* ps = Ps8 + (size_t)sd.x * SRCB;
        const unsigned char* pd = Pd8 + (size_t)sd.y * DSTB;

        // ---- issue all 14 gathers up front (all 16B, contiguous per region) ----
        uint4 a16[2], b16[2], zq[2];
        f16x8 zs[4], yv[4];
        a16[0] = *reinterpret_cast<const uint4*>(ps + g * 32);          // A' fp8
        a16[1] = *reinterpret_cast<const uint4*>(ps + g * 32 + 16);
        b16[0] = *reinterpret_cast<const uint4*>(pd + g * 32);          // B fp8
        b16[1] = *reinterpret_cast<const uint4*>(pd + g * 32 + 16);
        zq[0]  = *reinterpret_cast<const uint4*>(pd + 384 + g * 32);    // Zh8[dst]
        zq[1]  = *reinterpret_cast<const uint4*>(pd + 384 + g * 32 + 16);
#pragma unroll
        for (int kk = 0; kk < 4; ++kk) {
            const int of = g * 64 + kk * 16;
            zs[kk] = *reinterpret_cast<const f16x8*>(ps + 128 + of);    // Zh16[src]
            yv[kk] = *reinterpret_cast<const f16x8*>(pd + 128 + of);    // Y[dst]
        }
        const unsigned zdw[8] = { zq[0].x, zq[0].y, zq[0].z, zq[0].w,
                                  zq[1].x, zq[1].y, zq[1].z, zq[1].w };

        // ---- score1: H(16x64) = (zs .* fp8(zd)) @ Wh1^T via MFMA ----
        f32x4 acc[4] = {};
#pragma unroll
        for (int kk = 0; kk < 4; ++kk) {
            f32x2 p0 = __builtin_amdgcn_cvt_pk_f32_fp8((int)zdw[2 * kk], false);
            f32x2 p1 = __builtin_amdgcn_cvt_pk_f32_fp8((int)zdw[2 * kk], true);
            f32x2 p2 = __builtin_amdgcn_cvt_pk_f32_fp8((int)zdw[2 * kk + 1], false);
            f32x2 p3 = __builtin_amdgcn_cvt_pk_f32_fp8((int)zdw[2 * kk + 1], true);
            f16x8 a;
            a[0] = (_Float16)((float)zs[kk][0] * p0.x);
            a[1] = (_Float16)((float)zs[kk][1] * p0.y);
            a[2] = (_Float16)((float)zs[kk][2] * p1.x);
            a[3] = (_Float16)((float)zs[kk][3] * p1.y);
            a[4] = (_Float16)((float)zs[kk][4] * p2.x);
            a[5] = (_Float16)((float)zs[kk][5] * p2.y);
            a[6] = (_Float16)((float)zs[kk][6] * p3.x);
            a[7] = (_Float16)((float)zs[kk][7] * p3.y);
            mfma16(acc[0], a, myb[(0 * 4 + kk) * 64]);
            mfma16(acc[1], a, myb[(1 * 4 + kk) * 64]);
            mfma16(acc[2], a, myb[(2 * 4 + kk) * 64]);
            mfma16(acc[3], a, myb[(3 * 4 + kk) * 64]);
        }
        float t4[4];
#pragma unroll
        for (int rr = 0; rr < 4; ++rr) {
            float s = 0.f;
#pragma unroll
            for (int nt = 0; nt < 4; ++nt)
                s = fmaf(fmaxf(acc[nt][rr] + bh1v[nt], 0.f), wh2v[nt], s);
            t4[rr] = s;
        }
#pragma unroll
        for (int mask = 1; mask <= 8; mask <<= 1) {
#pragma unroll
            for (int rr = 0; rr < 4; ++rr)
                t4[rr] += __shfl_xor(t4[rr], mask, 16);
        }
        float u = t4[0];
        if (rsel == 1) u = t4[1];
        if (rsel == 2) u = t4[2];
        if (rsel == 3) u = t4[3];
        const float sc1w = __shfl(u, srcl, 64);  // W0-folded score1 of edge base+lane%16

        // ---- score2 (fp8 A'+B) & score3 (f16 zs . Y) ----
        float sA = 0.f, sB = 0.f;
#pragma unroll
        for (int h = 0; h < 2; ++h) {
            const unsigned ax = a16[h].x, ay = a16[h].y, az = a16[h].z, aw = a16[h].w;
            const unsigned bx = b16[h].x, by = b16[h].y, bz = b16[h].z, bw_ = b16[h].w;
            f32x2 pa0 = __builtin_amdgcn_cvt_pk_f32_fp8((int)ax, false);
            f32x2 pa1 = __builtin_amdgcn_cvt_pk_f32_fp8((int)ax, true);
            f32x2 pa2 = __builtin_amdgcn_cvt_pk_f32_fp8((int)ay, false);
            f32x2 pa3 = __builtin_amdgcn_cvt_pk_f32_fp8((int)ay, true);
            f32x2 pa4 = __builtin_amdgcn_cvt_pk_f32_fp8((int)az, false);
            f32x2 pa5 = __builtin_amdgcn_cvt_pk_f32_fp8((int)az, true);
            f32x2 pa6 = __builtin_amdgcn_cvt_pk_f32_fp8((int)aw, false);
            f32x2 pa7 = __builtin_amdgcn_cvt_pk_f32_fp8((int)aw, true);
            f32x2 pb0 = __builtin_amdgcn_cvt_pk_f32_fp8((int)bx, false);
            f32x2 pb1 = __builtin_amdgcn_cvt_pk_f32_fp8((int)bx, true);
            f32x2 pb2 = __builtin_amdgcn_cvt_pk_f32_fp8((int)by, false);
            f32x2 pb3 = __builtin_amdgcn_cvt_pk_f32_fp8((int)by, true);
            f32x2 pb4 = __builtin_amdgcn_cvt_pk_f32_fp8((int)bz, false);
            f32x2 pb5 = __builtin_amdgcn_cvt_pk_f32_fp8((int)bz, true);
            f32x2 pb6 = __builtin_amdgcn_cvt_pk_f32_fp8((int)bw_, false);
            f32x2 pb7 = __builtin_amdgcn_cvt_pk_f32_fp8((int)bw_, true);
            const f16x8 w0 = wc2r[2 * h], w1 = wc2r[2 * h + 1];
            sA = fmaf(fmaxf(pa0.x + pb0.x, 0.f), (float)w0[0], sA);
            sA = fmaf(fmaxf(pa0.y + pb0.y, 0.f), (float)w0[1], sA);
            sA = fmaf(fmaxf(pa1.x + pb1.x, 0.f), (float)w0[2], sA);
            sA = fmaf(fmaxf(pa1.y + pb1.y, 0.f), (float)w0[3], sA);
            sA = fmaf(fmaxf(pa2.x + pb2.x, 0.f), (float)w0[4], sA);
            sA = fmaf(fmaxf(pa2.y + pb2.y, 0.f), (float)w0[5], sA);
            sA = fmaf(fmaxf(pa3.x + pb3.x, 0.f), (float)w0[6], sA);
            sA = fmaf(fmaxf(pa3.y + pb3.y, 0.f), (float)w0[7], sA);
            sA = fmaf(fmaxf(pa4.x + pb4.x, 0.f), (float)w1[0], sA);
            sA = fmaf(fmaxf(pa4.y + pb4.y, 0.f), (float)w1[1], sA);
            sA = fmaf(fmaxf(pa5.x + pb5.x, 0.f), (float)w1[2], sA);
            sA = fmaf(fmaxf(pa5.y + pb5.y, 0.f), (float)w1[3], sA);
            sA = fmaf(fmaxf(pa6.x + pb6.x, 0.f), (float)w1[4], sA);
            sA = fmaf(fmaxf(pa6.y + pb6.y, 0.f), (float)w1[5], sA);
            sA = fmaf(fmaxf(pa7.x + pb7.x, 0.f), (float)w1[6], sA);
            sA = fmaf(fmaxf(pa7.y + pb7.y, 0.f), (float)w1[7], sA);
        }
#pragma unroll
        for (int kk = 0; kk < 4; ++kk)
#pragma unroll
            for (int j2 = 0; j2 < 4; ++j2)
                sB = fdot2(zs[kk], yv[kk], j2, sB);

        sA += __shfl_xor(sA, 16, 64);
        sA += __shfl_xor(sA, 32, 64);
        sB += __shfl_xor(sB, 16, 64);
        sB += __shfl_xor(sB, 32, 64);

        const float res = sc1w + sA + fmaf(W2, sB, cbias);
        if (lane < 16) out[base + lane] = res;
        sd = sdn;
    }
}

// ---------------- fallback: fused wave-per-edge, no workspace ----------------
__global__ __launch_bounds__(256) void fused_fallback(
    const float* __restrict__ z, const int* __restrict__ edge,
    const float* __restrict__ w_h1, const float* __restrict__ b_h1,
    const float* __restrict__ w_h2, const float* __restrict__ b_h2,
    const float* __restrict__ w_c1, const float* __restrict__ b_c1,
    const float* __restrict__ w_c2, const float* __restrict__ b_c2,
    const float* __restrict__ w_b, const float* __restrict__ b_b,
    const float* __restrict__ sw, float* __restrict__ out)
{
    __shared__ float zbuf[4][256];
    const int lane = threadIdx.x & 63;
    const int w = threadIdx.x >> 6;
    const int gw = blockIdx.x * 4 + w;
    const int nw = gridDim.x * 4;

    const float s0 = sw[0], s1 = sw[1], s2 = sw[2];
    const float mx = fmaxf(s0, fmaxf(s1, s2));
    const float e0 = __expf(s0 - mx), e1 = __expf(s1 - mx), e2 = __expf(s2 - mx);
    const float inv = 1.0f / (e0 + e1 + e2);
    const float W0 = e0 * inv, W1 = e1 * inv, W2 = e2 * inv;
    const float cbias = W0 * b_h2[0] + W1 * b_c2[0] + W2 * b_b[0];

    for (int e = gw; e < N_EDGES; e += nw) {
        const int src = edge[2 * e], dst = edge[2 * e + 1];
        const float zs0 = z[(size_t)src * 128 + lane];
        const float zs1 = z[(size_t)src * 128 + 64 + lane];
        const float zd0 = z[(size_t)dst * 128 + lane];
        const float zd1 = z[(size_t)dst * 128 + 64 + lane];
        zbuf[w][lane] = zs0; zbuf[w][64 + lane] = zs1;
        zbuf[w][128 + lane] = zd0; zbuf[w][192 + lane] = zd1;
        asm volatile("s_waitcnt lgkmcnt(0)" ::: "memory");

        float h = 0.f;
        const float* whr = w_h1 + (size_t)lane * 128;
        for (int d = 0; d < 128; ++d)
            h = fmaf(zbuf[w][d] * zbuf[w][128 + d], whr[d], h);
        float sc1 = fmaxf(h + b_h1[lane], 0.f) * w_h2[lane];

        float c0 = 0.f, c1 = 0.f;
        const float* w0r = w_c1 + (size_t)lane * 256;
        const float* w1r = w_c1 + (size_t)(lane + 64) * 256;
        for (int d = 0; d < 256; ++d) {
            const float cat = zbuf[w][d];
            c0 = fmaf(cat, w0r[d], c0);
            c1 = fmaf(cat, w1r[d], c1);
        }
        float sc2 = fmaxf(c0 + b_c1[lane], 0.f) * w_c2[lane]
                  + fmaxf(c1 + b_c1[lane + 64], 0.f) * w_c2[lane + 64];

        float t0 = 0.f, t1 = 0.f;
        const float* wb0 = w_b + (size_t)lane * 128;
        const float* wb1 = w_b + (size_t)(lane + 64) * 128;
        for (int f = 0; f < 128; ++f) {
            const float zdf = zbuf[w][128 + f];
            t0 = fmaf(wb0[f], zdf, t0);
            t1 = fmaf(wb1[f], zdf, t1);
        }
        float sc3 = zs0 * t0 + zs1 * t1;

        float v = fmaf(W0, sc1, fmaf(W1, sc2, W2 * sc3));
#pragma unroll
        for (int m = 1; m < 64; m <<= 1) v += __shfl_xor(v, m, 64);
        if (lane == 0) out[e] = v + cbias;
    }
}

extern "C" void kernel_launch(void* const* d_in, const int* in_sizes, int n_in,
                              void* d_out, int out_size, void* d_ws, size_t ws_size,
                              hipStream_t stream)
{
    const float* z    = (const float*)d_in[0];
    const int*   edge = (const int*)d_in[1];
    const float* w_h1 = (const float*)d_in[2];
    const float* b_h1 = (const float*)d_in[3];
    const float* w_h2 = (const float*)d_in[4];
    const float* b_h2 = (const float*)d_in[5];
    const float* w_c1 = (const float*)d_in[6];
    const float* b_c1 = (const float*)d_in[7];
    const float* w_c2 = (const float*)d_in[8];
    const float* b_c2 = (const float*)d_in[9];
    const float* w_b  = (const float*)d_in[10];
    const float* b_b  = (const float*)d_in[11];
    const float* sw   = (const float*)d_in[12];
    float* outp = (float*)d_out;

    const size_t szSrc = (size_t)N_NODES * SRCB;   // 38,400,000
    const size_t szDst = (size_t)N_NODES * DSTB;   // 51,200,000
    const size_t need  = szSrc + szDst;            // 89.6 MB

    if (ws_size >= need) {
        unsigned char* Ps8 = (unsigned char*)d_ws;
        unsigned char* Pd8 = (unsigned char*)d_ws + szSrc;
        hipLaunchKernelGGL(precomp_kernel, dim3(512), dim3(512), 0, stream,
                           z, w_c1, b_c1, w_b, Ps8, Pd8);
        hipLaunchKernelGGL(edge_kernel, dim3(1024), dim3(256), 0, stream,
                           (const int2*)edge, Ps8, Pd8, w_h1, b_h1, w_h2, b_h2,
                           w_c2, b_c2, b_b, sw, outp);
    } else {
        hipLaunchKernelGGL(fused_fallback, dim3(4096), dim3(256), 0, stream,
                           z, edge, w_h1, b_h1, w_h2, b_h2, w_c1, b_c1,
                           w_c2, b_c2, w_b, b_b, sw, outp);
    }
}

// Round 13
// 178.687 us; speedup vs baseline: 4.2946x; 1.0558x over previous
//
#include <hip/hip_runtime.h>
#include <hip/hip_bf16.h>

#define N_NODES 100000
#define N_EDGES 1000000
// SoA node tables in d_ws:
//   P_src[node] (384B): [A' fp8e4m3 x128 | Zh16 f16 x128]   (A' = Wc1a@z + b_c1)
//   P_dst[node] (512B): [B  fp8e4m3 x128 | Y f16 x128 | Zh8 fp8 x128]
//     B = Wc1b@z (bias folded into A'), Y = Wb@z
// Edge-kernel k-map (lane g, mfma kk, elem j): k = g*32 + kk*8 + j
#define SRCB 384
#define DSTB 512
#define NB (N_EDGES / 16)       // 62500
#define NCHUNK (N_NODES / 16)   // 6250

typedef float f32x4 __attribute__((ext_vector_type(4)));
typedef float f32x2 __attribute__((ext_vector_type(2)));
typedef _Float16 f16x8 __attribute__((ext_vector_type(8)));
typedef _Float16 f16x2 __attribute__((ext_vector_type(2)));

__device__ inline f16x8 pack8(float4 a, float4 b) {
    f16x8 o;
    o[0] = (_Float16)a.x; o[1] = (_Float16)a.y; o[2] = (_Float16)a.z; o[3] = (_Float16)a.w;
    o[4] = (_Float16)b.x; o[5] = (_Float16)b.y; o[6] = (_Float16)b.z; o[7] = (_Float16)b.w;
    return o;
}
__device__ inline unsigned long long pkfp8x8(float4 a, float4 b) {
    int q0 = __builtin_amdgcn_cvt_pk_fp8_f32(a.x, a.y, 0, false);
    q0 = __builtin_amdgcn_cvt_pk_fp8_f32(a.z, a.w, q0, true);
    int q1 = __builtin_amdgcn_cvt_pk_fp8_f32(b.x, b.y, 0, false);
    q1 = __builtin_amdgcn_cvt_pk_fp8_f32(b.z, b.w, q1, true);
    return ((unsigned long long)(unsigned)q1 << 32) | (unsigned)q0;
}
__device__ inline void mfma16(f32x4& acc, f16x8 a, f16x8 b) {
    acc = __builtin_amdgcn_mfma_f32_16x16x32_f16(a, b, acc, 0, 0, 0);
}
__device__ inline void mfma8(f32x4& acc, long a, long b) {
    acc = __builtin_amdgcn_mfma_f32_16x16x32_fp8_fp8(a, b, acc, 0, 0, 0);
}
__device__ inline float fdot2(f16x8 a, f16x8 b, int j2, float c) {
    f16x2 pa = { a[2 * j2], a[2 * j2 + 1] };
    f16x2 pb = { b[2 * j2], b[2 * j2 + 1] };
    return __builtin_amdgcn_fdot2(pa, pb, c, false);
}
__device__ inline unsigned char f2fp8(float v) {
    int p = __builtin_amdgcn_cvt_pk_fp8_f32(v, v, 0, false);
    return (unsigned char)(p & 0xff);
}

// ---- precompute v5: single pass, z read once. LDS weights: fp8 for A'/B tiles
// (ct 0-3, 32KB), f16 for Y tiles (ct 4-5, 32KB). No per-chunk barriers.
__global__ __launch_bounds__(512) void precomp_kernel(
    const float* __restrict__ z, const float* __restrict__ w_c1,
    const float* __restrict__ b_c1, const float* __restrict__ w_b,
    unsigned char* __restrict__ Ps8, unsigned char* __restrict__ Pd8)
{
    __shared__ unsigned long long w8[4096];   // 32 KB: ct0-3 x nt x kk x 64 lanes
    __shared__ f16x8 w16[2048];               // 32 KB: ct4-5 x nt x kk x 64 lanes

    const int tid = threadIdx.x;
    const int w = tid >> 6;
    const int lane = tid & 63;
    const int r = lane & 15, g = lane >> 4;
    const int gw = blockIdx.x * 8 + w;
    const int nW = gridDim.x * 8;

    float bc1v[2][4];
#pragma unroll
    for (int t = 0; t < 2; ++t)
#pragma unroll
        for (int nt = 0; nt < 4; ++nt)
            bc1v[t][nt] = b_c1[t * 64 + nt * 16 + r];

    // stage fp8 weight tiles (ct 0-3): idx ((t*4+nt)*4+kk)*64 + g*16 + r
    for (int i = tid; i < 4096; i += 512) {
        const int r_ = i & 15, g_ = (i >> 4) & 3, kk = (i >> 6) & 3;
        const int nt = (i >> 8) & 3, t = i >> 10;
        const int c = t * 64 + nt * 16 + r_;
        const float* wrow = (c < 128) ? (w_c1 + (size_t)c * 256)
                                      : (w_c1 + (size_t)(c - 128) * 256 + 128);
        const int k0 = kk * 32 + g_ * 8;
        float4 f0 = *reinterpret_cast<const float4*>(wrow + k0);
        float4 f1 = *reinterpret_cast<const float4*>(wrow + k0 + 4);
        w8[i] = pkfp8x8(f0, f1);
    }
    // stage f16 weight tiles (ct 4-5): idx ((t*4+nt)*4+kk)*64 + g*16 + r
    for (int i = tid; i < 2048; i += 512) {
        const int r_ = i & 15, g_ = (i >> 4) & 3, kk = (i >> 6) & 3;
        const int nt = (i >> 8) & 3, t = i >> 10;
        const int c = (4 + t) * 64 + nt * 16 + r_;
        const float* wrow = w_b + (size_t)(c - 256) * 128;
        const int k0 = kk * 32 + g_ * 8;
        float4 f0 = *reinterpret_cast<const float4*>(wrow + k0);
        float4 f1 = *reinterpret_cast<const float4*>(wrow + k0 + 4);
        w16[i] = pack8(f0, f1);
    }
    __syncthreads();

    const unsigned long long* myw8 = w8 + g * 16 + r;
    const f16x8* myw16 = w16 + g * 16 + r;

    for (int nb = gw; nb < NCHUNK; nb += nW) {
        const int node_r = nb * 16 + r;
        const float* zp = z + (size_t)node_r * 128;
        f16x8 a16[4];
        unsigned long long a8[4];
#pragma unroll
        for (int kk = 0; kk < 4; ++kk) {
            const int k0 = kk * 32 + g * 8;
            float4 z0 = *reinterpret_cast<const float4*>(zp + k0);
            float4 z1 = *reinterpret_cast<const float4*>(zp + k0 + 4);
            a16[kk] = pack8(z0, z1);
            a8[kk] = pkfp8x8(z0, z1);
            // fused Zh16 (src) + Zh8 (dst) writes
            *reinterpret_cast<f16x8*>(
                Ps8 + (size_t)node_r * SRCB + 128 + k0 * 2) = a16[kk];
            *reinterpret_cast<unsigned long long*>(
                Pd8 + (size_t)node_r * DSTB + 384 + k0) = a8[kk];
        }
        // fp8 tiles: ct 0-3 (A', B)
#pragma unroll
        for (int t = 0; t < 4; ++t) {
            f32x4 acc[4] = {};
#pragma unroll
            for (int kk = 0; kk < 4; ++kk) {
#pragma unroll
                for (int nt = 0; nt < 4; ++nt)
                    mfma8(acc[nt], (long)a8[kk],
                          (long)myw8[((t * 4 + nt) * 4 + kk) * 64]);
            }
#pragma unroll
            for (int nt = 0; nt < 4; ++nt) {
#pragma unroll
                for (int rr = 0; rr < 4; ++rr) {
                    const int node = nb * 16 + g * 4 + rr;
                    const int c = t * 64 + nt * 16 + r;
                    float v = acc[nt][rr];
                    if (t < 2) {
                        v += bc1v[t][nt];
                        Ps8[(size_t)node * SRCB + c] = f2fp8(v);            // A'
                    } else {
                        Pd8[(size_t)node * DSTB + (c - 128)] = f2fp8(v);    // B
                    }
                }
            }
        }
        // f16 tiles: ct 4-5 (Y)
#pragma unroll
        for (int t = 0; t < 2; ++t) {
            f32x4 acc[4] = {};
#pragma unroll
            for (int kk = 0; kk < 4; ++kk) {
#pragma unroll
                for (int nt = 0; nt < 4; ++nt)
                    mfma16(acc[nt], a16[kk], myw16[((t * 4 + nt) * 4 + kk) * 64]);
            }
#pragma unroll
            for (int nt = 0; nt < 4; ++nt) {
#pragma unroll
                for (int rr = 0; rr < 4; ++rr) {
                    const int node = nb * 16 + g * 4 + rr;
                    const int c = (4 + t) * 64 + nt * 16 + r;
                    *reinterpret_cast<_Float16*>(
                        Pd8 + (size_t)node * DSTB + 128
                            + (size_t)(c - 256) * 2) = (_Float16)acc[nt][rr];  // Y
                }
            }
        }
    }
}

// ---- main edge kernel (unchanged from round 11/12; measured 140us / 422MB) ----
// lane = g*16 + r : edge = b*16 + r; k(kk,g,j) = g*32 + kk*8 + j
__global__ __launch_bounds__(256) void edge_kernel(
    const int2* __restrict__ edge2,
    const unsigned char* __restrict__ Ps8, const unsigned char* __restrict__ Pd8,
    const float* __restrict__ w_h1, const float* __restrict__ b_h1,
    const float* __restrict__ w_h2, const float* __restrict__ b_h2,
    const float* __restrict__ w_c2, const float* __restrict__ b_c2,
    const float* __restrict__ b_b, const float* __restrict__ sw,
    float* __restrict__ out)
{
    __shared__ f16x8 bwlds[1024];   // entry (nt,kk,g,r): w_h1[nt*16+r][g*32+kk*8 ..+8]

    const int tid = threadIdx.x;
    for (int e = tid; e < 1024; e += 256) {
        const int r_ = e & 15, g_ = (e >> 4) & 3, kkf = (e >> 6) & 3, ntf = e >> 8;
        const float* wr = w_h1 + (size_t)(ntf * 16 + r_) * 128 + g_ * 32 + kkf * 8;
        float4 f0 = *reinterpret_cast<const float4*>(wr);
        float4 f1 = *reinterpret_cast<const float4*>(wr + 4);
        bwlds[e] = pack8(f0, f1);
    }
    __syncthreads();

    const int lane = tid & 63;
    const int r = lane & 15, g = lane >> 4;

    const float s0 = sw[0], s1 = sw[1], s2 = sw[2];
    const float mx = fmaxf(s0, fmaxf(s1, s2));
    const float e0 = __expf(s0 - mx), e1 = __expf(s1 - mx), e2 = __expf(s2 - mx);
    const float inv = 1.0f / (e0 + e1 + e2);
    const float W0 = e0 * inv, W1 = e1 * inv, W2 = e2 * inv;
    const float cbias = W0 * b_h2[0] + W1 * b_c2[0] + W2 * b_b[0];

    float bh1v[4], wh2v[4];
#pragma unroll
    for (int nt = 0; nt < 4; ++nt) {
        bh1v[nt] = b_h1[nt * 16 + r];
        wh2v[nt] = w_h2[nt * 16 + r] * W0;   // W0 folded
    }
    f16x8 wc2r[4];                            // wc2r[kk][j] = W1 * w_c2[g*32+kk*8+j]
#pragma unroll
    for (int kk = 0; kk < 4; ++kk) {
        const int k0 = g * 32 + kk * 8;
        float4 f0 = *reinterpret_cast<const float4*>(w_c2 + k0);
        float4 f1 = *reinterpret_cast<const float4*>(w_c2 + k0 + 4);
        f0.x *= W1; f0.y *= W1; f0.z *= W1; f0.w *= W1;
        f1.x *= W1; f1.y *= W1; f1.z *= W1; f1.w *= W1;
        wc2r[kk] = pack8(f0, f1);
    }
    const f16x8* myb = bwlds + g * 16 + r;

    const int gwid = (blockIdx.x * blockDim.x + tid) >> 6;
    const int nW = (gridDim.x * blockDim.x) >> 6;
    const int rsel = r & 3;
    const int srcl = ((r >> 2) << 4) | r;

    int b = gwid;
    int2 sd = make_int2(0, 0);
    if (b < NB) sd = edge2[b * 16 + r];

    for (; b < NB; b += nW) {
        const int bn = b + nW;
        int2 sdn = sd;
        if (bn < NB) sdn = edge2[bn * 16 + r];   // prefetch next iter's indices

        const int base = b * 16;
        const unsigned char* ps = Ps8 + (size_t)sd.x * SRCB;
        const unsigned char* pd = Pd8 + (size_t)sd.y * DSTB;

        // ---- issue all 14 gathers up front (all 16B, contiguous per region) ----
        uint4 a16[2], b16[2], zq[2];
        f16x8 zs[4], yv[4];
        a16[0] = *reinterpret_cast<const uint4*>(ps + g * 32);          // A' fp8
        a16[1] = *reinterpret_cast<const uint4*>(ps + g * 32 + 16);
        b16[0] = *reinterpret_cast<const uint4*>(pd + g * 32);          // B fp8
        b16[1] = *reinterpret_cast<const uint4*>(pd + g * 32 + 16);
        zq[0]  = *reinterpret_cast<const uint4*>(pd + 384 + g * 32);    // Zh8[dst]
        zq[1]  = *reinterpret_cast<const uint4*>(pd + 384 + g * 32 + 16);
#pragma unroll
        for (int kk = 0; kk < 4; ++kk) {
            const int of = g * 64 + kk * 16;
            zs[kk] = *reinterpret_cast<const f16x8*>(ps + 128 + of);    // Zh16[src]
            yv[kk] = *reinterpret_cast<const f16x8*>(pd + 128 + of);    // Y[dst]
        }
        const unsigned zdw[8] = { zq[0].x, zq[0].y, zq[0].z, zq[0].w,
                                  zq[1].x, zq[1].y, zq[1].z, zq[1].w };

        // ---- score1: H(16x64) = (zs .* fp8(zd)) @ Wh1^T via MFMA ----
        f32x4 acc[4] = {};
#pragma unroll
        for (int kk = 0; kk < 4; ++kk) {
            f32x2 p0 = __builtin_amdgcn_cvt_pk_f32_fp8((int)zdw[2 * kk], false);
            f32x2 p1 = __builtin_amdgcn_cvt_pk_f32_fp8((int)zdw[2 * kk], true);
            f32x2 p2 = __builtin_amdgcn_cvt_pk_f32_fp8((int)zdw[2 * kk + 1], false);
            f32x2 p3 = __builtin_amdgcn_cvt_pk_f32_fp8((int)zdw[2 * kk + 1], true);
            f16x8 a;
            a[0] = (_Float16)((float)zs[kk][0] * p0.x);
            a[1] = (_Float16)((float)zs[kk][1] * p0.y);
            a[2] = (_Float16)((float)zs[kk][2] * p1.x);
            a[3] = (_Float16)((float)zs[kk][3] * p1.y);
            a[4] = (_Float16)((float)zs[kk][4] * p2.x);
            a[5] = (_Float16)((float)zs[kk][5] * p2.y);
            a[6] = (_Float16)((float)zs[kk][6] * p3.x);
            a[7] = (_Float16)((float)zs[kk][7] * p3.y);
            mfma16(acc[0], a, myb[(0 * 4 + kk) * 64]);
            mfma16(acc[1], a, myb[(1 * 4 + kk) * 64]);
            mfma16(acc[2], a, myb[(2 * 4 + kk) * 64]);
            mfma16(acc[3], a, myb[(3 * 4 + kk) * 64]);
        }
        float t4[4];
#pragma unroll
        for (int rr = 0; rr < 4; ++rr) {
            float s = 0.f;
#pragma unroll
            for (int nt = 0; nt < 4; ++nt)
                s = fmaf(fmaxf(acc[nt][rr] + bh1v[nt], 0.f), wh2v[nt], s);
            t4[rr] = s;
        }
#pragma unroll
        for (int mask = 1; mask <= 8; mask <<= 1) {
#pragma unroll
            for (int rr = 0; rr < 4; ++rr)
                t4[rr] += __shfl_xor(t4[rr], mask, 16);
        }
        float u = t4[0];
        if (rsel == 1) u = t4[1];
        if (rsel == 2) u = t4[2];
        if (rsel == 3) u = t4[3];
        const float sc1w = __shfl(u, srcl, 64);  // W0-folded score1 of edge base+lane%16

        // ---- score2 (fp8 A'+B) & score3 (f16 zs . Y) ----
        float sA = 0.f, sB = 0.f;
#pragma unroll
        for (int h = 0; h < 2; ++h) {
            const unsigned ax = a16[h].x, ay = a16[h].y, az = a16[h].z, aw = a16[h].w;
            const unsigned bx = b16[h].x, by = b16[h].y, bz = b16[h].z, bw_ = b16[h].w;
            f32x2 pa0 = __builtin_amdgcn_cvt_pk_f32_fp8((int)ax, false);
            f32x2 pa1 = __builtin_amdgcn_cvt_pk_f32_fp8((int)ax, true);
            f32x2 pa2 = __builtin_amdgcn_cvt_pk_f32_fp8((int)ay, false);
            f32x2 pa3 = __builtin_amdgcn_cvt_pk_f32_fp8((int)ay, true);
            f32x2 pa4 = __builtin_amdgcn_cvt_pk_f32_fp8((int)az, false);
            f32x2 pa5 = __builtin_amdgcn_cvt_pk_f32_fp8((int)az, true);
            f32x2 pa6 = __builtin_amdgcn_cvt_pk_f32_fp8((int)aw, false);
            f32x2 pa7 = __builtin_amdgcn_cvt_pk_f32_fp8((int)aw, true);
            f32x2 pb0 = __builtin_amdgcn_cvt_pk_f32_fp8((int)bx, false);
            f32x2 pb1 = __builtin_amdgcn_cvt_pk_f32_fp8((int)bx, true);
            f32x2 pb2 = __builtin_amdgcn_cvt_pk_f32_fp8((int)by, false);
            f32x2 pb3 = __builtin_amdgcn_cvt_pk_f32_fp8((int)by, true);
            f32x2 pb4 = __builtin_amdgcn_cvt_pk_f32_fp8((int)bz, false);
            f32x2 pb5 = __builtin_amdgcn_cvt_pk_f32_fp8((int)bz, true);
            f32x2 pb6 = __builtin_amdgcn_cvt_pk_f32_fp8((int)bw_, false);
            f32x2 pb7 = __builtin_amdgcn_cvt_pk_f32_fp8((int)bw_, true);
            const f16x8 w0 = wc2r[2 * h], w1 = wc2r[2 * h + 1];
            sA = fmaf(fmaxf(pa0.x + pb0.x, 0.f), (float)w0[0], sA);
            sA = fmaf(fmaxf(pa0.y + pb0.y, 0.f), (float)w0[1], sA);
            sA = fmaf(fmaxf(pa1.x + pb1.x, 0.f), (float)w0[2], sA);
            sA = fmaf(fmaxf(pa1.y + pb1.y, 0.f), (float)w0[3], sA);
            sA = fmaf(fmaxf(pa2.x + pb2.x, 0.f), (float)w0[4], sA);
            sA = fmaf(fmaxf(pa2.y + pb2.y, 0.f), (float)w0[5], sA);
            sA = fmaf(fmaxf(pa3.x + pb3.x, 0.f), (float)w0[6], sA);
            sA = fmaf(fmaxf(pa3.y + pb3.y, 0.f), (float)w0[7], sA);
            sA = fmaf(fmaxf(pa4.x + pb4.x, 0.f), (float)w1[0], sA);
            sA = fmaf(fmaxf(pa4.y + pb4.y, 0.f), (float)w1[1], sA);
            sA = fmaf(fmaxf(pa5.x + pb5.x, 0.f), (float)w1[2], sA);
            sA = fmaf(fmaxf(pa5.y + pb5.y, 0.f), (float)w1[3], sA);
            sA = fmaf(fmaxf(pa6.x + pb6.x, 0.f), (float)w1[4], sA);
            sA = fmaf(fmaxf(pa6.y + pb6.y, 0.f), (float)w1[5], sA);
            sA = fmaf(fmaxf(pa7.x + pb7.x, 0.f), (float)w1[6], sA);
            sA = fmaf(fmaxf(pa7.y + pb7.y, 0.f), (float)w1[7], sA);
        }
#pragma unroll
        for (int kk = 0; kk < 4; ++kk)
#pragma unroll
            for (int j2 = 0; j2 < 4; ++j2)
                sB = fdot2(zs[kk], yv[kk], j2, sB);

        sA += __shfl_xor(sA, 16, 64);
        sA += __shfl_xor(sA, 32, 64);
        sB += __shfl_xor(sB, 16, 64);
        sB += __shfl_xor(sB, 32, 64);

        const float res = sc1w + sA + fmaf(W2, sB, cbias);
        if (lane < 16) out[base + lane] = res;
        sd = sdn;
    }
}

// ---------------- fallback: fused wave-per-edge, no workspace ----------------
__global__ __launch_bounds__(256) void fused_fallback(
    const float* __restrict__ z, const int* __restrict__ edge,
    const float* __restrict__ w_h1, const float* __restrict__ b_h1,
    const float* __restrict__ w_h2, const float* __restrict__ b_h2,
    const float* __restrict__ w_c1, const float* __restrict__ b_c1,
    const float* __restrict__ w_c2, const float* __restrict__ b_c2,
    const float* __restrict__ w_b, const float* __restrict__ b_b,
    const float* __restrict__ sw, float* __restrict__ out)
{
    __shared__ float zbuf[4][256];
    const int lane = threadIdx.x & 63;
    const int w = threadIdx.x >> 6;
    const int gw = blockIdx.x * 4 + w;
    const int nw = gridDim.x * 4;

    const float s0 = sw[0], s1 = sw[1], s2 = sw[2];
    const float mx = fmaxf(s0, fmaxf(s1, s2));
    const float e0 = __expf(s0 - mx), e1 = __expf(s1 - mx), e2 = __expf(s2 - mx);
    const float inv = 1.0f / (e0 + e1 + e2);
    const float W0 = e0 * inv, W1 = e1 * inv, W2 = e2 * inv;
    const float cbias = W0 * b_h2[0] + W1 * b_c2[0] + W2 * b_b[0];

    for (int e = gw; e < N_EDGES; e += nw) {
        const int src = edge[2 * e], dst = edge[2 * e + 1];
        const float zs0 = z[(size_t)src * 128 + lane];
        const float zs1 = z[(size_t)src * 128 + 64 + lane];
        const float zd0 = z[(size_t)dst * 128 + lane];
        const float zd1 = z[(size_t)dst * 128 + 64 + lane];
        zbuf[w][lane] = zs0; zbuf[w][64 + lane] = zs1;
        zbuf[w][128 + lane] = zd0; zbuf[w][192 + lane] = zd1;
        asm volatile("s_waitcnt lgkmcnt(0)" ::: "memory");

        float h = 0.f;
        const float* whr = w_h1 + (size_t)lane * 128;
        for (int d = 0; d < 128; ++d)
            h = fmaf(zbuf[w][d] * zbuf[w][128 + d], whr[d], h);
        float sc1 = fmaxf(h + b_h1[lane], 0.f) * w_h2[lane];

        float c0 = 0.f, c1 = 0.f;
        const float* w0r = w_c1 + (size_t)lane * 256;
        const float* w1r = w_c1 + (size_t)(lane + 64) * 256;
        for (int d = 0; d < 256; ++d) {
            const float cat = zbuf[w][d];
            c0 = fmaf(cat, w0r[d], c0);
            c1 = fmaf(cat, w1r[d], c1);
        }
        float sc2 = fmaxf(c0 + b_c1[lane], 0.f) * w_c2[lane]
                  + fmaxf(c1 + b_c1[lane + 64], 0.f) * w_c2[lane + 64];

        float t0 = 0.f, t1 = 0.f;
        const float* wb0 = w_b + (size_t)lane * 128;
        const float* wb1 = w_b + (size_t)(lane + 64) * 128;
        for (int f = 0; f < 128; ++f) {
            const float zdf = zbuf[w][128 + f];
            t0 = fmaf(wb0[f], zdf, t0);
            t1 = fmaf(wb1[f], zdf, t1);
        }
        float sc3 = zs0 * t0 + zs1 * t1;

        float v = fmaf(W0, sc1, fmaf(W1, sc2, W2 * sc3));
#pragma unroll
        for (int m = 1; m < 64; m <<= 1) v += __shfl_xor(v, m, 64);
        if (lane == 0) out[e] = v + cbias;
    }
}

extern "C" void kernel_launch(void* const* d_in, const int* in_sizes, int n_in,
                              void* d_out, int out_size, void* d_ws, size_t ws_size,
                              hipStream_t stream)
{
    const float* z    = (const float*)d_in[0];
    const int*   edge = (const int*)d_in[1];
    const float* w_h1 = (const float*)d_in[2];
    const float* b_h1 = (const float*)d_in[3];
    const float* w_h2 = (const float*)d_in[4];
    const float* b_h2 = (const float*)d_in[5];
    const float* w_c1 = (const float*)d_in[6];
    const float* b_c1 = (const float*)d_in[7];
    const float* w_c2 = (const float*)d_in[8];
    const float* b_c2 = (const float*)d_in[9];
    const float* w_b  = (const float*)d_in[10];
    const float* b_b  = (const float*)d_in[11];
    const float* sw   = (const float*)d_in[12];
    float* outp = (float*)d_out;

    const size_t szSrc = (size_t)N_NODES * SRCB;   // 38,400,000
    const size_t szDst = (size_t)N_NODES * DSTB;   // 51,200,000
    const size_t need  = szSrc + szDst;            // 89.6 MB

    if (ws_size >= need) {
        unsigned char* Ps8 = (unsigned char*)d_ws;
        unsigned char* Pd8 = (unsigned char*)d_ws + szSrc;
        // 64KB LDS -> 2 blocks/CU; 512 blocks = full co-residency
        hipLaunchKernelGGL(precomp_kernel, dim3(512), dim3(512), 0, stream,
                           z, w_c1, b_c1, w_b, Ps8, Pd8);
        hipLaunchKernelGGL(edge_kernel, dim3(1024), dim3(256), 0, stream,
                           (const int2*)edge, Ps8, Pd8, w_h1, b_h1, w_h2, b_h2,
                           w_c2, b_c2, b_b, sw, outp);
    } else {
        hipLaunchKernelGGL(fused_fallback, dim3(4096), dim3(256), 0, stream,
                           z, edge, w_h1, b_h1, w_h2, b_h2, w_c1, b_c1,
                           w_c2, b_c2, w_b, b_b, sw, outp);
    }
}